// Round 1
// 572.404 us; speedup vs baseline: 1.0054x; 1.0054x over previous
//
#include <hip/hip_runtime.h>
#include <hip/hip_bf16.h>
#include <stdint.h>

#define N_NODES 50000
#define N_EDGES 800000
#define NL 2

// K strides (bf16 elements)
#define KS2 136   // 128-K GEMMs: 4 k-steps, stride 136
#define KSU 264   // upd GEMM1: K=256 (8 k-steps), stride 264
#define ESTR 133  // edge_kernel fp32 LDS stride: bank=(5m+c)%32, conflict-free

typedef __bf16 bf16x8 __attribute__((ext_vector_type(8)));
typedef float f32x4 __attribute__((ext_vector_type(4)));

__device__ __forceinline__ f32x4 mfma_bf16(uint4 a, uint4 b, f32x4 c) {
    return __builtin_amdgcn_mfma_f32_16x16x32_bf16(
        __builtin_bit_cast(bf16x8, a), __builtin_bit_cast(bf16x8, b), c, 0, 0, 0);
}

__device__ __forceinline__ unsigned short f2b(float f) {
    union { float f; unsigned u; } v; v.f = f;
    unsigned r = v.u + 0x7FFFu + ((v.u >> 16) & 1u);   // RNE
    return (unsigned short)(r >> 16);
}

__device__ __forceinline__ float b2f(unsigned short u) {
    union { unsigned u; float f; } v; v.u = ((unsigned)u) << 16; return v.f;
}
__device__ __forceinline__ float b2f_lo(unsigned u) {
    union { unsigned u; float f; } v; v.u = u << 16; return v.f;
}
__device__ __forceinline__ float b2f_hi(unsigned u) {
    union { unsigned u; float f; } v; v.u = u & 0xFFFF0000u; return v.f;
}

// Per-wave 16-row x 128-col tile (head_kernel).
template<int KSTEPS, int BSTR>
__device__ __forceinline__ void gemm8(const unsigned short* aLane,
                                      const unsigned short* bLane, f32x4 acc[8]) {
#pragma unroll
    for (int kc = 0; kc < KSTEPS; kc++) {
        uint4 a = *(const uint4*)(aLane + kc * 32);
#pragma unroll
        for (int ct = 0; ct < 8; ct++) {
            uint4 b = *(const uint4*)(bLane + (size_t)ct * 16 * BSTR + kc * 32);
            acc[ct] = mfma_bf16(a, b, acc[ct]);
        }
    }
}

// Column-split wave tile: 64 rows (4 rt) x 32 cols (2 ct) per wave (upd_kernel).
template<int KSTEPS, int ASTR, int BSTR>
__device__ __forceinline__ void gemm_2x4(const unsigned short* aLane,
                                         const unsigned short* bLane,
                                         f32x4 acc[4][2]) {
#pragma unroll
    for (int kc = 0; kc < KSTEPS; kc++) {
        uint4 b0 = *(const uint4*)(bLane + kc * 32);
        uint4 b1 = *(const uint4*)(bLane + (size_t)16 * BSTR + kc * 32);
#pragma unroll
        for (int rt = 0; rt < 4; rt++) {
            uint4 a = *(const uint4*)(aLane + (size_t)rt * 16 * ASTR + kc * 32);
            acc[rt][0] = mfma_bf16(a, b0, acc[rt][0]);
            acc[rt][1] = mfma_bf16(a, b1, acc[rt][1]);
        }
    }
}

// ---------------- weight prep ----------------
__global__ void prep_kernel(const float* __restrict__ mW1,
                            const float* __restrict__ uW1, const float* __restrict__ uW2,
                            const float* __restrict__ hW,
                            unsigned short* __restrict__ wab, unsigned short* __restrict__ w1cp,
                            unsigned short* __restrict__ u1t, unsigned short* __restrict__ u2t,
                            unsigned short* __restrict__ ht) {
    int i = blockIdx.x * 256 + threadIdx.x;
    const int SA = NL * 256 * 136;
    const int SC = NL * 128 * 32;
    const int SU = NL * 128 * KSU;
    const int S3 = NL * 128 * KS2;
    const int S4 = 128 * KS2;
    if (i < SA) {
        int l = i / (256 * 136), r = i % (256 * 136), j = r / 136, k = r % 136;
        float v = 0.f;
        if (k < 128)
            v = (j < 128) ? mW1[((size_t)l * 272 + k) * 128 + j]
                          : mW1[((size_t)l * 272 + 128 + k) * 128 + (j - 128)];
        wab[i] = f2b(v);
        return;
    }
    i -= SA;
    if (i < SC) {
        int l = i / (128 * 32), r = i % (128 * 32), j = r / 32, k = r % 32;
        w1cp[i] = (k < 16) ? f2b(mW1[((size_t)l * 272 + 256 + k) * 128 + j]) : (unsigned short)0;
        return;
    }
    i -= SC;
    if (i < SU) {
        int l = i / (128 * KSU), r = i % (128 * KSU), n = r / KSU, k = r % KSU;
        if (k < 128)       u1t[i] = f2b(uW1[((size_t)l * 256 + k) * 128 + n]);
        else if (k >= 256) u1t[i] = 0;
        return;
    }
    i -= SU;
    if (i < S3) {
        int l = i / (128 * KS2), r = i % (128 * KS2), n = r / KS2, k = r % KS2;
        u2t[i] = (k < 128) ? f2b(uW2[((size_t)l * 128 + k) * 128 + n]) : (unsigned short)0;
        return;
    }
    i -= S3;
    if (i < S4) {
        int n = i / KS2, k = i % KS2;
        ht[i] = (k < 128) ? f2b(hW[(size_t)k * 128 + n]) : (unsigned short)0;
    }
}

// ---------------- prep2: u1t[l][n][128+j] = bf16( sum_c W2[l][j][c] * U1[l][128+c][n] )
__global__ void prep2_kernel(const float* __restrict__ mW2, const float* __restrict__ uW1,
                             unsigned short* __restrict__ u1t) {
    __shared__ float w2row[128];
    const int l = blockIdx.x >> 7, j = blockIdx.x & 127;
    const int n = threadIdx.x;
    w2row[n] = mW2[((size_t)l * 128 + j) * 128 + n];
    __syncthreads();
    float s = 0.f;
#pragma unroll 8
    for (int c = 0; c < 128; c++)
        s += w2row[c] * uW1[((size_t)l * 256 + 128 + c) * 128 + n];
    u1t[(size_t)l * 128 * KSU + (size_t)n * KSU + 128 + j] = f2b(s);
}

// ---------------- prep3: bfold[l][n] = sum_c b2[l][c] * U1[l][128+c][n]
__global__ void prep3_kernel(const float* __restrict__ mb2, const float* __restrict__ uW1,
                             float* __restrict__ bfold) {
    const int l = blockIdx.x;
    const int n = threadIdx.x;
    float s = 0.f;
#pragma unroll 8
    for (int c = 0; c < 128; c++)
        s += mb2[l * 128 + c] * uW1[((size_t)l * 256 + 128 + c) * 128 + n];
    bfold[l * 128 + n] = s;
}

// ---------------- encoder: relu(x@W+b) -> LN ----------------
__global__ __launch_bounds__(256) void enc_kernel(
        const float* __restrict__ x, const float* __restrict__ W,
        const float* __restrict__ b, const float* __restrict__ g, const float* __restrict__ bet,
        float* __restrict__ h, unsigned short* __restrict__ hb) {
    __shared__ float sx[64];
    __shared__ float redS[4], redSS[4];
    const int t = threadIdx.x;
    const int nb = blockIdx.x * 2;           // 2 nodes / block; 25000 blocks exact
    if (t < 64) sx[t] = x[(size_t)nb * 32 + t];
    __syncthreads();
    const int half = t >> 7, j = t & 127;
    const int node = nb + half;
    float acc = b[j];
#pragma unroll
    for (int k = 0; k < 32; k++) acc += sx[half * 32 + k] * W[k * 128 + j];
    float v = fmaxf(acc, 0.f);
    float s = v, ss = v * v;
#pragma unroll
    for (int d = 32; d > 0; d >>= 1) { s += __shfl_down(s, d); ss += __shfl_down(ss, d); }
    const int wv = t >> 6;
    if ((t & 63) == 0) { redS[wv] = s; redSS[wv] = ss; }
    __syncthreads();
    float S = redS[half * 2] + redS[half * 2 + 1];
    float SS = redSS[half * 2] + redSS[half * 2 + 1];
    float mu = S * (1.f / 128.f);
    float var = SS * (1.f / 128.f) - mu * mu;
    float rs = rsqrtf(var + 1e-5f);
    float o = (v - mu) * rs * g[j] + bet[j];
    h[(size_t)node * 128 + j] = o;
    hb[(size_t)node * 128 + j] = f2b(o);
}

// ---------------- counting sort of edges by target ----------------
__global__ void hist_kernel(const int* __restrict__ tgt, int* __restrict__ hist) {
    int i = blockIdx.x * 256 + threadIdx.x;   // E = 3125*256 exact
    atomicAdd(hist + tgt[i], 1);
}

__global__ void scan1_kernel(const int* __restrict__ hist, int* __restrict__ incl,
                             int* __restrict__ blksum) {
    __shared__ int buf[256];
    const int t = threadIdx.x;
    const int i = blockIdx.x * 256 + t;
    int v = (i < N_NODES) ? hist[i] : 0;
    buf[t] = v; __syncthreads();
#pragma unroll
    for (int d = 1; d < 256; d <<= 1) {
        int x = (t >= d) ? buf[t - d] : 0;
        __syncthreads();
        buf[t] += x;
        __syncthreads();
    }
    if (i < N_NODES) incl[i] = buf[t];
    if (t == 255) blksum[blockIdx.x] = buf[255];
}

__global__ void scan2_kernel(int* __restrict__ blksum, int nblk) {
    __shared__ int buf[256];
    const int t = threadIdx.x;
    int v = (t < nblk) ? blksum[t] : 0;
    buf[t] = v; __syncthreads();
#pragma unroll
    for (int d = 1; d < 256; d <<= 1) {
        int x = (t >= d) ? buf[t - d] : 0;
        __syncthreads();
        buf[t] += x;
        __syncthreads();
    }
    if (t < nblk) blksum[t] = buf[t];
}

__global__ void scan3_kernel(int* __restrict__ incl, const int* __restrict__ blksum,
                             const int* __restrict__ hist) {
    const int i = blockIdx.x * 256 + threadIdx.x;
    if (i >= N_NODES) return;
    const int b = blockIdx.x;
    const int base = (b > 0) ? blksum[b - 1] : 0;
    incl[i] = incl[i] + base - hist[i];
}

__global__ void scatter_kernel(const int* __restrict__ src, const int* __restrict__ tgt,
                               const float* __restrict__ ea, int* __restrict__ cursor,
                               unsigned short* __restrict__ sSrc, unsigned short* __restrict__ sTgt,
                               unsigned short* __restrict__ eabS) {
    const int e = blockIdx.x * 256 + threadIdx.x;   // E exact
    const int tg = tgt[e];
    const int p = atomicAdd(cursor + tg, 1);
    sSrc[p] = (unsigned short)src[e];
    sTgt[p] = (unsigned short)tg;
    const float4* s = (const float4*)(ea + (size_t)e * 16);
    ushort4* d = (ushort4*)(eabS + (size_t)p * 16);
#pragma unroll
    for (int i = 0; i < 4; i++) {
        float4 v = s[i];
        d[i] = make_ushort4(f2b(v.x), f2b(v.y), f2b(v.z), f2b(v.w));
    }
}

// ---------------- per-layer node GEMM: T = h@W1a + b1, S = h@W1b ----------------
__global__ __launch_bounds__(256, 4) void node_kernel(
        const unsigned short* __restrict__ hb, const unsigned short* __restrict__ wab,
        const float* __restrict__ b1,
        unsigned short* __restrict__ Tb, unsigned short* __restrict__ Sb) {
    __shared__ __align__(16) unsigned short As[64 * KS2];
    const int t = threadIdx.x;
    const int n0 = blockIdx.x * 64;
    {
        const int m = t >> 2, q = t & 3;
        const int node = n0 + m;
        uint4* dst = (uint4*)(As + m * KS2);
        if (node < N_NODES) {
            const uint4* s = (const uint4*)(hb + (size_t)node * 128);
#pragma unroll
            for (int i = 0; i < 4; i++) dst[q * 4 + i] = s[q * 4 + i];
        } else {
            uint4 z{0, 0, 0, 0};
            for (int i = q; i < 16; i += 4) dst[i] = z;
        }
    }
    __syncthreads();

    const int wv = t >> 6, lane = t & 63, lr = lane & 15, lq = lane >> 4;
    const int cb = wv * 64;
    const f32x4 z4 = {0.f, 0.f, 0.f, 0.f};
    f32x4 acc[4][4];                     // [rt][ct]
#pragma unroll
    for (int i = 0; i < 4; i++)
#pragma unroll
        for (int j = 0; j < 4; j++) acc[i][j] = z4;

    const unsigned short* aL = As + lr * KS2 + lq * 8;
    const unsigned short* bL = wab + (size_t)(cb + lr) * KS2 + lq * 8;
#pragma unroll
    for (int kc = 0; kc < 4; kc++) {
        uint4 bA = *(const uint4*)(bL + kc * 32);
        uint4 bB = *(const uint4*)(bL + (size_t)16 * KS2 + kc * 32);
        uint4 bC = *(const uint4*)(bL + (size_t)32 * KS2 + kc * 32);
        uint4 bD = *(const uint4*)(bL + (size_t)48 * KS2 + kc * 32);
#pragma unroll
        for (int rt = 0; rt < 4; rt++) {
            uint4 a = *(const uint4*)(aL + (size_t)rt * 16 * KS2 + kc * 32);
            acc[rt][0] = mfma_bf16(a, bA, acc[rt][0]);
            acc[rt][1] = mfma_bf16(a, bB, acc[rt][1]);
            acc[rt][2] = mfma_bf16(a, bC, acc[rt][2]);
            acc[rt][3] = mfma_bf16(a, bD, acc[rt][3]);
        }
    }
#pragma unroll
    for (int ct = 0; ct < 4; ct++) {
        const int j = cb + ct * 16 + lr;
        const float bias = (j < 128) ? b1[j] : 0.f;
#pragma unroll
        for (int rt = 0; rt < 4; rt++) {
#pragma unroll
            for (int r = 0; r < 4; r++) {
                const int node = n0 + rt * 16 + lq * 4 + r;
                if (node < N_NODES) {
                    const float v = acc[rt][ct][r] + bias;
                    if (j < 128) Tb[(size_t)node * 128 + j] = f2b(v);
                    else         Sb[(size_t)node * 128 + (j - 128)] = f2b(v);
                }
            }
        }
    }
}

// ---------------- edge kernel: relu(T[tgt]+S[src]+ea@W1c) + segmented sum ----------------
// 64 edges/block processed as TWO 32-edge half-tiles over one fp32 LDS buffer
// Es[32][ESTR] (17 KB total LDS -> 8 blocks/CU, 32 waves/CU vs 4 blocks before).
// Per half:
//  P1: 4 waves, each (row-tile 16 x col-block 64): MFMA ea@W1c, fp32 scatter to Es.
//  P2: thread = (edge m = t&31, chunk c8b = t>>5); lane pairs read ADJACENT 16B
//      chunks of the same gathered Tb/Sb row (32B/row per wave instr); Es += T+S, relu.
//  P3: segmented fp32 sum over sorted targets; half 0 uses even-t col threads
//      (rows 0..31), half 1 odd-t (rows 32..63) -> split points (0,32) identical to
//      the old kernel, so atomic count to aggr is unchanged.
__global__ __launch_bounds__(256, 8) void edge_kernel(
        const unsigned short* __restrict__ eabS,
        const unsigned short* __restrict__ sSrc, const unsigned short* __restrict__ sTgt,
        const unsigned short* __restrict__ w1cp,
        const unsigned short* __restrict__ Tb, const unsigned short* __restrict__ Sb,
        float* __restrict__ aggr) {
    __shared__ __align__(16) float Es[32 * ESTR];
    __shared__ int sT[64];
    __shared__ int sS[64];

    const int t = threadIdx.x;
    const int e0 = blockIdx.x * 64;          // E = 12500*64 exact
    if (t < 64) { sT[t] = sTgt[e0 + t]; sS[t] = sSrc[e0 + t]; }

    const int wv = t >> 6, lane = t & 63, lr = lane & 15, lq = lane >> 4;
    const int rtw = (wv >> 1) * 16;          // row-tile base within half: 0 or 16
    const int cbw = (wv & 1) * 64;           // col-block base: 0 or 64
    const f32x4 z4 = {0.f, 0.f, 0.f, 0.f};

#pragma unroll
    for (int h = 0; h < 2; h++) {
        if (h) __syncthreads();              // Es reuse: P3(h=0) done before P1(h=1)

        {   // Phase 1: wave (rtw,cbw) -> 16 edges x 64 cols, 4 MFMAs
            uint4 a = {0, 0, 0, 0};
            if (lq < 2)
                a = *(const uint4*)(eabS + (size_t)(e0 + h * 32 + rtw + lr) * 16 + lq * 8);
            f32x4 acc[4];
#pragma unroll
            for (int ct = 0; ct < 4; ct++) {
                uint4 b = *(const uint4*)(w1cp + (cbw + ct * 16 + lr) * 32 + lq * 8);
                acc[ct] = mfma_bf16(a, b, z4);
            }
#pragma unroll
            for (int ct = 0; ct < 4; ct++) {
                const int col = cbw + ct * 16 + lr;
#pragma unroll
                for (int r = 0; r < 4; r++)
                    Es[(rtw + lq * 4 + r) * ESTR + col] = acc[ct][r];
            }
        }
        __syncthreads();

        {   // Phase 2: thread -> edge m = t&31 (within half), chunks c8b + {0,8}
            const int m = t & 31;
            const int c8b = t >> 5;
            const int ge = h * 32 + m;
            const unsigned short* Trow = Tb + (size_t)sT[ge] * 128;
            const unsigned short* Srow = Sb + (size_t)sS[ge] * 128;
            float* Erow = Es + m * ESTR;
#pragma unroll
            for (int it = 0; it < 2; it++) {
                const int c0 = (c8b + it * 8) * 8;
                const uint4 tv = *(const uint4*)(Trow + c0);
                const uint4 sv = *(const uint4*)(Srow + c0);
                float tf[8] = {b2f_lo(tv.x), b2f_hi(tv.x), b2f_lo(tv.y), b2f_hi(tv.y),
                               b2f_lo(tv.z), b2f_hi(tv.z), b2f_lo(tv.w), b2f_hi(tv.w)};
                float sf[8] = {b2f_lo(sv.x), b2f_hi(sv.x), b2f_lo(sv.y), b2f_hi(sv.y),
                               b2f_lo(sv.z), b2f_hi(sv.z), b2f_lo(sv.w), b2f_hi(sv.w)};
#pragma unroll
                for (int i = 0; i < 8; i++)
                    Erow[c0 + i] = fmaxf(Erow[c0 + i] + tf[i] + sf[i], 0.f);
            }
        }
        __syncthreads();

        if ((t & 1) == h) {   // Phase 3: 128 col-threads, rows h*32 .. h*32+31
            const int c = t >> 1;
            float s = 0.f;
            int cur = sT[h * 32];
            for (int i = 0; i < 32; i++) {
                const int tg = sT[h * 32 + i];
                if (tg != cur) {
                    atomicAdd(aggr + (size_t)cur * 128 + c, s);
                    s = 0.f; cur = tg;
                }
                s += Es[i * ESTR + c];
            }
            atomicAdd(aggr + (size_t)cur * 128 + c, s);
        }
    }
}

// ---------------- update MLP + residual + LN ----------------
__global__ __launch_bounds__(256, 4) void upd_kernel(
        const unsigned short* __restrict__ hb_in, const float* __restrict__ h_in,
        const float* __restrict__ aggr, const int* __restrict__ hist,
        const unsigned short* __restrict__ u1t, const unsigned short* __restrict__ u2t,
        const float* __restrict__ b1, const float* __restrict__ bf,
        const float* __restrict__ b2,
        const float* __restrict__ g, const float* __restrict__ bet,
        float* __restrict__ h_out, unsigned short* __restrict__ hb_out) {
    __shared__ __align__(16) char smemA[64 * KSU * 2];
    __shared__ float sF[64];
    unsigned short* As = (unsigned short*)smemA;
    float* LNb = (float*)smemA;

    const int t = threadIdx.x;
    const int n0 = blockIdx.x * 64;
    {
        const int m = t >> 2, q = t & 3;
        const int node = n0 + m;
        unsigned short* row = As + m * KSU;
        if (node < N_NODES) {
            const uint4* ph = (const uint4*)(hb_in + (size_t)node * 128);
            uint4* d0 = (uint4*)row;
#pragma unroll
            for (int i = 0; i < 4; i++) d0[q * 4 + i] = ph[q * 4 + i];
            const int cntv = hist[node];
            if (q == 0) sF[m] = (cntv > 0) ? 1.f : 0.f;
            const float rden = 1.0f / fmaxf((float)cntv, 1.0f);
            const float4* pa = (const float4*)(aggr + (size_t)node * 128 + q * 32);
            ushort4* d1 = (ushort4*)(row + 128 + q * 32);
#pragma unroll
            for (int i = 0; i < 8; i++) {
                float4 v = pa[i];
                d1[i] = make_ushort4(f2b(v.x * rden), f2b(v.y * rden),
                                     f2b(v.z * rden), f2b(v.w * rden));
            }
            if (q == 0) { uint4 z{0, 0, 0, 0}; ((uint4*)(row + 256))[0] = z; }
        } else {
            if (q == 0) sF[m] = 0.f;
            uint4 z{0, 0, 0, 0};
            uint4* d = (uint4*)row;
            for (int i = q; i < 33; i += 4) d[i] = z;
        }
    }
    __syncthreads();

    const int wv = t >> 6, lane = t & 63, lr = lane & 15, lq = lane >> 4;
    const int cb = wv * 32;
    const f32x4 z4 = {0.f, 0.f, 0.f, 0.f};

    f32x4 acc[4][2];
#pragma unroll
    for (int i = 0; i < 4; i++) { acc[i][0] = z4; acc[i][1] = z4; }
    gemm_2x4<8, KSU, KSU>(As + lr * KSU + lq * 8,
                          u1t + (size_t)(cb + lr) * KSU + lq * 8, acc);
    __syncthreads();

#pragma unroll
    for (int ct = 0; ct < 2; ct++) {
        const int col = cb + ct * 16 + lr;
        const float bv = b1[col];
        const float bfv = bf[col];
#pragma unroll
        for (int rt = 0; rt < 4; rt++) {
#pragma unroll
            for (int r = 0; r < 4; r++) {
                const int ml = rt * 16 + lq * 4 + r;
                float v = fmaxf(acc[rt][ct][r] + bv + sF[ml] * bfv, 0.f);
                As[ml * KSU + col] = f2b(v);
            }
        }
    }
    __syncthreads();

    f32x4 acc2[4][2];
#pragma unroll
    for (int i = 0; i < 4; i++) { acc2[i][0] = z4; acc2[i][1] = z4; }
    gemm_2x4<4, KSU, KS2>(As + lr * KSU + lq * 8,
                          u2t + (size_t)(cb + lr) * KS2 + lq * 8, acc2);
    __syncthreads();

    // residual add into LN staging fp32 [64][132]
#pragma unroll
    for (int ct = 0; ct < 2; ct++) {
        const int col = cb + ct * 16 + lr;
        const float bv = b2[col];
#pragma unroll
        for (int rt = 0; rt < 4; rt++) {
#pragma unroll
            for (int r = 0; r < 4; r++) {
                const int ml = rt * 16 + lq * 4 + r;
                const int node = n0 + ml;
                if (node < N_NODES)
                    LNb[ml * 132 + col] = acc2[rt][ct][r] + bv + h_in[(size_t)node * 128 + col];
            }
        }
    }
    __syncthreads();

    {   // LayerNorm: 4 threads per row
        const int r = t >> 2, c0 = (t & 3) * 32;
        const int node = n0 + r;
        if (node < N_NODES) {
            float s = 0.f, ss = 0.f;
#pragma unroll
            for (int i = 0; i < 32; i++) { float v = LNb[r * 132 + c0 + i]; s += v; ss += v * v; }
            s += __shfl_xor(s, 1); ss += __shfl_xor(ss, 1);
            s += __shfl_xor(s, 2); ss += __shfl_xor(ss, 2);
            const float mu = s * (1.0f / 128.0f);
            const float var = ss * (1.0f / 128.0f) - mu * mu;
            const float rs = rsqrtf(var + 1e-5f);
#pragma unroll
            for (int i = 0; i < 32; i++) {
                const int j = c0 + i;
                float v = (LNb[r * 132 + j] - mu) * rs * g[j] + bet[j];
                h_out[(size_t)node * 128 + j] = v;
                hb_out[(size_t)node * 128 + j] = f2b(v);
            }
        }
    }
}

// ---------------- head GEMM ----------------
__global__ __launch_bounds__(256, 2) void head_kernel(
        const unsigned short* __restrict__ hb, const unsigned short* __restrict__ ht,
        const float* __restrict__ hbias, float* __restrict__ out) {
    __shared__ __align__(16) unsigned short As[64 * KS2];
    const int t = threadIdx.x;
    const int n0 = blockIdx.x * 64;
    {
        const int m = t >> 2, q = t & 3;
        const int node = n0 + m;
        uint4* dst = (uint4*)(As + m * KS2);
        if (node < N_NODES) {
            const uint4* s = (const uint4*)(hb + (size_t)node * 128);
#pragma unroll
            for (int i = 0; i < 4; i++) dst[q * 4 + i] = s[q * 4 + i];
        } else {
            uint4 z{0, 0, 0, 0};
            for (int i = q; i < 16; i += 4) dst[i] = z;
        }
    }
    __syncthreads();

    const int wv = t >> 6, lane = t & 63, lr = lane & 15, lq = lane >> 4;
    const int m0 = wv * 16;
    const f32x4 z4 = {0.f, 0.f, 0.f, 0.f};
    f32x4 acc[8];
#pragma unroll
    for (int i = 0; i < 8; i++) acc[i] = z4;
    gemm8<4, KS2>(As + (m0 + lr) * KS2 + lq * 8, ht + (size_t)lr * KS2 + lq * 8, acc);
#pragma unroll
    for (int ct = 0; ct < 8; ct++) {
        const int col = ct * 16 + lr;
        const float bv = hbias[col];
#pragma unroll
        for (int r = 0; r < 4; r++) {
            const int node = n0 + m0 + lq * 4 + r;
            if (node < N_NODES) out[(size_t)node * 128 + col] = acc[ct][r] + bv;
        }
    }
}

extern "C" void kernel_launch(void* const* d_in, const int* in_sizes, int n_in,
                              void* d_out, int out_size, void* d_ws, size_t ws_size,
                              hipStream_t stream) {
    const float* x       = (const float*)d_in[0];
    const int*   ei      = (const int*)d_in[1];
    const float* ea      = (const float*)d_in[2];
    const float* encW    = (const float*)d_in[3];
    const float* encb    = (const float*)d_in[4];
    const float* encg    = (const float*)d_in[5];
    const float* encbeta = (const float*)d_in[6];
    const float* msgW1   = (const float*)d_in[7];
    const float* msgb1   = (const float*)d_in[8];
    const float* msgW2   = (const float*)d_in[9];
    const float* msgb2   = (const float*)d_in[10];
    const float* updW1   = (const float*)d_in[11];
    const float* updb1   = (const float*)d_in[12];
    const float* updW2   = (const float*)d_in[13];
    const float* updb2   = (const float*)d_in[14];
    const float* lng     = (const float*)d_in[15];
    const float* lnbeta  = (const float*)d_in[16];
    const float* headW   = (const float*)d_in[17];
    const float* headb   = (const float*)d_in[18];

    char* w = (char*)d_ws;
    size_t off = 0;
    auto nxt = [&](size_t bytes) -> void* {
        void* p = w + off;
        off = (off + bytes + 255) & ~(size_t)255;
        return p;
    };
    float*          h     = (float*)nxt((size_t)N_NODES * 128 * 4);
    unsigned short* hb    = (unsigned short*)nxt((size_t)N_NODES * 128 * 2);
    float*          aggr  = (float*)nxt((size_t)N_NODES * 128 * 4);
    unsigned short* Tb    = (unsigned short*)nxt((size_t)N_NODES * 128 * 2);
    unsigned short* Sb    = (unsigned short*)nxt((size_t)N_NODES * 128 * 2);
    unsigned short* eabS  = (unsigned short*)nxt((size_t)N_EDGES * 16 * 2);
    unsigned short* sSrc  = (unsigned short*)nxt((size_t)N_EDGES * 2);
    unsigned short* sTgtS = (unsigned short*)nxt((size_t)N_EDGES * 2);
    int*            hist  = (int*)nxt((size_t)N_NODES * 4);
    int*            incl  = (int*)nxt((size_t)N_NODES * 4);   // becomes cursor
    int*            blksum= (int*)nxt(256 * 4);
    unsigned short* wab   = (unsigned short*)nxt((size_t)NL * 256 * 136 * 2);
    unsigned short* w1cp  = (unsigned short*)nxt((size_t)NL * 128 * 32 * 2);
    unsigned short* u1t   = (unsigned short*)nxt((size_t)NL * 128 * KSU * 2);
    unsigned short* u2t   = (unsigned short*)nxt((size_t)NL * 128 * KS2 * 2);
    unsigned short* ht    = (unsigned short*)nxt((size_t)128 * KS2 * 2);
    float*          bfold = (float*)nxt((size_t)NL * 128 * 4);

    const int NBLK = (N_NODES + 255) / 256;   // 196
    const int PREP_N = NL * 256 * 136 + NL * 128 * 32 + NL * 128 * KSU
                     + NL * 128 * KS2 + 128 * KS2;

    hipMemsetAsync(hist, 0, (size_t)N_NODES * 4, stream);
    prep_kernel<<<(PREP_N + 255) / 256, 256, 0, stream>>>(msgW1, updW1, updW2, headW,
                                                          wab, w1cp, u1t, u2t, ht);
    prep2_kernel<<<NL * 128, 128, 0, stream>>>(msgW2, updW1, u1t);
    prep3_kernel<<<NL, 128, 0, stream>>>(msgb2, updW1, bfold);
    enc_kernel<<<25000, 256, 0, stream>>>(x, encW, encb, encg, encbeta, h, hb);
    hist_kernel<<<3125, 256, 0, stream>>>(ei + N_EDGES, hist);
    scan1_kernel<<<NBLK, 256, 0, stream>>>(hist, incl, blksum);
    scan2_kernel<<<1, 256, 0, stream>>>(blksum, NBLK);
    scan3_kernel<<<NBLK, 256, 0, stream>>>(incl, blksum, hist);
    scatter_kernel<<<3125, 256, 0, stream>>>(ei, ei + N_EDGES, ea, incl,
                                             sSrc, sTgtS, eabS);

    for (int l = 0; l < NL; l++) {
        node_kernel<<<782, 256, 0, stream>>>(hb, wab + (size_t)l * 256 * 136,
                                             msgb1 + l * 128, Tb, Sb);
        hipMemsetAsync(aggr, 0, (size_t)N_NODES * 128 * 4, stream);
        edge_kernel<<<12500, 256, 0, stream>>>(eabS, sSrc, sTgtS,
                                               w1cp + (size_t)l * 128 * 32,
                                               Tb, Sb, aggr);
        upd_kernel<<<782, 256, 0, stream>>>(hb, h, aggr, hist,
                                            u1t + (size_t)l * 128 * KSU,
                                            u2t + (size_t)l * 128 * KS2,
                                            updb1 + l * 128, bfold + l * 128,
                                            updb2 + l * 128,
                                            lng + l * 128, lnbeta + l * 128, h, hb);
    }
    head_kernel<<<782, 256, 0, stream>>>(hb, ht, headb, (float*)d_out);
}

// Round 2
// 567.054 us; speedup vs baseline: 1.0149x; 1.0094x over previous
//
#include <hip/hip_runtime.h>
#include <hip/hip_bf16.h>
#include <stdint.h>

#define N_NODES 50000
#define N_EDGES 800000
#define NL 2

// K strides (bf16 elements)
#define KS2 136   // 128-K GEMMs: 4 k-steps, stride 136
#define KSU 264   // upd GEMM1: K=256 (8 k-steps), stride 264
#define ESTR 133  // edge_kernel fp32 LDS stride: bank=(5m+c)%32, conflict-free

typedef __bf16 bf16x8 __attribute__((ext_vector_type(8)));
typedef float f32x4 __attribute__((ext_vector_type(4)));

__device__ __forceinline__ f32x4 mfma_bf16(uint4 a, uint4 b, f32x4 c) {
    return __builtin_amdgcn_mfma_f32_16x16x32_bf16(
        __builtin_bit_cast(bf16x8, a), __builtin_bit_cast(bf16x8, b), c, 0, 0, 0);
}

__device__ __forceinline__ unsigned short f2b(float f) {
    union { float f; unsigned u; } v; v.f = f;
    unsigned r = v.u + 0x7FFFu + ((v.u >> 16) & 1u);   // RNE
    return (unsigned short)(r >> 16);
}

__device__ __forceinline__ float b2f(unsigned short u) {
    union { unsigned u; float f; } v; v.u = ((unsigned)u) << 16; return v.f;
}
__device__ __forceinline__ float b2f_lo(unsigned u) {
    union { unsigned u; float f; } v; v.u = u << 16; return v.f;
}
__device__ __forceinline__ float b2f_hi(unsigned u) {
    union { unsigned u; float f; } v; v.u = u & 0xFFFF0000u; return v.f;
}

// Per-wave 16-row x 128-col tile (head_kernel).
template<int KSTEPS, int BSTR>
__device__ __forceinline__ void gemm8(const unsigned short* aLane,
                                      const unsigned short* bLane, f32x4 acc[8]) {
#pragma unroll
    for (int kc = 0; kc < KSTEPS; kc++) {
        uint4 a = *(const uint4*)(aLane + kc * 32);
#pragma unroll
        for (int ct = 0; ct < 8; ct++) {
            uint4 b = *(const uint4*)(bLane + (size_t)ct * 16 * BSTR + kc * 32);
            acc[ct] = mfma_bf16(a, b, acc[ct]);
        }
    }
}

// Column-split wave tile: 64 rows (4 rt) x 32 cols (2 ct) per wave (upd_kernel).
template<int KSTEPS, int ASTR, int BSTR>
__device__ __forceinline__ void gemm_2x4(const unsigned short* aLane,
                                         const unsigned short* bLane,
                                         f32x4 acc[4][2]) {
#pragma unroll
    for (int kc = 0; kc < KSTEPS; kc++) {
        uint4 b0 = *(const uint4*)(bLane + kc * 32);
        uint4 b1 = *(const uint4*)(bLane + (size_t)16 * BSTR + kc * 32);
#pragma unroll
        for (int rt = 0; rt < 4; rt++) {
            uint4 a = *(const uint4*)(aLane + (size_t)rt * 16 * ASTR + kc * 32);
            acc[rt][0] = mfma_bf16(a, b0, acc[rt][0]);
            acc[rt][1] = mfma_bf16(a, b1, acc[rt][1]);
        }
    }
}

// ---------------- weight prep ----------------
__global__ void prep_kernel(const float* __restrict__ mW1,
                            const float* __restrict__ uW1, const float* __restrict__ uW2,
                            const float* __restrict__ hW,
                            unsigned short* __restrict__ wab, unsigned short* __restrict__ w1cp,
                            unsigned short* __restrict__ u1t, unsigned short* __restrict__ u2t,
                            unsigned short* __restrict__ ht) {
    int i = blockIdx.x * 256 + threadIdx.x;
    const int SA = NL * 256 * 136;
    const int SC = NL * 128 * 32;
    const int SU = NL * 128 * KSU;
    const int S3 = NL * 128 * KS2;
    const int S4 = 128 * KS2;
    if (i < SA) {
        int l = i / (256 * 136), r = i % (256 * 136), j = r / 136, k = r % 136;
        float v = 0.f;
        if (k < 128)
            v = (j < 128) ? mW1[((size_t)l * 272 + k) * 128 + j]
                          : mW1[((size_t)l * 272 + 128 + k) * 128 + (j - 128)];
        wab[i] = f2b(v);
        return;
    }
    i -= SA;
    if (i < SC) {
        int l = i / (128 * 32), r = i % (128 * 32), j = r / 32, k = r % 32;
        w1cp[i] = (k < 16) ? f2b(mW1[((size_t)l * 272 + 256 + k) * 128 + j]) : (unsigned short)0;
        return;
    }
    i -= SC;
    if (i < SU) {
        int l = i / (128 * KSU), r = i % (128 * KSU), n = r / KSU, k = r % KSU;
        if (k < 128)       u1t[i] = f2b(uW1[((size_t)l * 256 + k) * 128 + n]);
        else if (k >= 256) u1t[i] = 0;
        return;
    }
    i -= SU;
    if (i < S3) {
        int l = i / (128 * KS2), r = i % (128 * KS2), n = r / KS2, k = r % KS2;
        u2t[i] = (k < 128) ? f2b(uW2[((size_t)l * 128 + k) * 128 + n]) : (unsigned short)0;
        return;
    }
    i -= S3;
    if (i < S4) {
        int n = i / KS2, k = i % KS2;
        ht[i] = (k < 128) ? f2b(hW[(size_t)k * 128 + n]) : (unsigned short)0;
    }
}

// ---------------- prep2: u1t[l][n][128+j] = bf16( sum_c W2[l][j][c] * U1[l][128+c][n] )
__global__ void prep2_kernel(const float* __restrict__ mW2, const float* __restrict__ uW1,
                             unsigned short* __restrict__ u1t) {
    __shared__ float w2row[128];
    const int l = blockIdx.x >> 7, j = blockIdx.x & 127;
    const int n = threadIdx.x;
    w2row[n] = mW2[((size_t)l * 128 + j) * 128 + n];
    __syncthreads();
    float s = 0.f;
#pragma unroll 8
    for (int c = 0; c < 128; c++)
        s += w2row[c] * uW1[((size_t)l * 256 + 128 + c) * 128 + n];
    u1t[(size_t)l * 128 * KSU + (size_t)n * KSU + 128 + j] = f2b(s);
}

// ---------------- prep3: bfold[l][n] = sum_c b2[l][c] * U1[l][128+c][n]
__global__ void prep3_kernel(const float* __restrict__ mb2, const float* __restrict__ uW1,
                             float* __restrict__ bfold) {
    const int l = blockIdx.x;
    const int n = threadIdx.x;
    float s = 0.f;
#pragma unroll 8
    for (int c = 0; c < 128; c++)
        s += mb2[l * 128 + c] * uW1[((size_t)l * 256 + 128 + c) * 128 + n];
    bfold[l * 128 + n] = s;
}

// ---------------- encoder: relu(x@W+b) -> LN ----------------
__global__ __launch_bounds__(256) void enc_kernel(
        const float* __restrict__ x, const float* __restrict__ W,
        const float* __restrict__ b, const float* __restrict__ g, const float* __restrict__ bet,
        float* __restrict__ h, unsigned short* __restrict__ hb) {
    __shared__ float sx[64];
    __shared__ float redS[4], redSS[4];
    const int t = threadIdx.x;
    const int nb = blockIdx.x * 2;           // 2 nodes / block; 25000 blocks exact
    if (t < 64) sx[t] = x[(size_t)nb * 32 + t];
    __syncthreads();
    const int half = t >> 7, j = t & 127;
    const int node = nb + half;
    float acc = b[j];
#pragma unroll
    for (int k = 0; k < 32; k++) acc += sx[half * 32 + k] * W[k * 128 + j];
    float v = fmaxf(acc, 0.f);
    float s = v, ss = v * v;
#pragma unroll
    for (int d = 32; d > 0; d >>= 1) { s += __shfl_down(s, d); ss += __shfl_down(ss, d); }
    const int wv = t >> 6;
    if ((t & 63) == 0) { redS[wv] = s; redSS[wv] = ss; }
    __syncthreads();
    float S = redS[half * 2] + redS[half * 2 + 1];
    float SS = redSS[half * 2] + redSS[half * 2 + 1];
    float mu = S * (1.f / 128.f);
    float var = SS * (1.f / 128.f) - mu * mu;
    float rs = rsqrtf(var + 1e-5f);
    float o = (v - mu) * rs * g[j] + bet[j];
    h[(size_t)node * 128 + j] = o;
    hb[(size_t)node * 128 + j] = f2b(o);
}

// ---------------- counting sort of edges by target ----------------
__global__ void hist_kernel(const int* __restrict__ tgt, int* __restrict__ hist) {
    int i = blockIdx.x * 256 + threadIdx.x;   // E = 3125*256 exact
    atomicAdd(hist + tgt[i], 1);
}

__global__ void scan1_kernel(const int* __restrict__ hist, int* __restrict__ incl,
                             int* __restrict__ blksum) {
    __shared__ int buf[256];
    const int t = threadIdx.x;
    const int i = blockIdx.x * 256 + t;
    int v = (i < N_NODES) ? hist[i] : 0;
    buf[t] = v; __syncthreads();
#pragma unroll
    for (int d = 1; d < 256; d <<= 1) {
        int x = (t >= d) ? buf[t - d] : 0;
        __syncthreads();
        buf[t] += x;
        __syncthreads();
    }
    if (i < N_NODES) incl[i] = buf[t];
    if (t == 255) blksum[blockIdx.x] = buf[255];
}

__global__ void scan2_kernel(int* __restrict__ blksum, int nblk) {
    __shared__ int buf[256];
    const int t = threadIdx.x;
    int v = (t < nblk) ? blksum[t] : 0;
    buf[t] = v; __syncthreads();
#pragma unroll
    for (int d = 1; d < 256; d <<= 1) {
        int x = (t >= d) ? buf[t - d] : 0;
        __syncthreads();
        buf[t] += x;
        __syncthreads();
    }
    if (t < nblk) blksum[t] = buf[t];
}

__global__ void scan3_kernel(int* __restrict__ incl, const int* __restrict__ blksum,
                             const int* __restrict__ hist) {
    const int i = blockIdx.x * 256 + threadIdx.x;
    if (i >= N_NODES) return;
    const int b = blockIdx.x;
    const int base = (b > 0) ? blksum[b - 1] : 0;
    incl[i] = incl[i] + base - hist[i];
}

// ---------------- sort step 1: 8B random scatter of {edge id, packed src|tgt} ------
// Replaces the old 36B/edge random scatter (110 MB HBM writes from partial-line
// dirties). Ordering within a target segment = atomic arrival order, same as before.
__global__ void scatterp_kernel(const int* __restrict__ src, const int* __restrict__ tgt,
                                int* __restrict__ cursor, uint2* __restrict__ permst) {
    const int e = blockIdx.x * 256 + threadIdx.x;   // E exact
    const int tg = tgt[e];
    const int p = atomicAdd(cursor + tg, 1);
    permst[p] = make_uint2((unsigned)e, ((unsigned)src[e] << 16) | (unsigned)tg);
}

// ---------------- sort step 2: coalesced gather + bf16 convert --------------------
// thread p: read permst[p] (coalesced), gather 64B ea row for edge e (random read,
// ea is 51.2MB -> L3-resident), write eabS[p] 32B + sST[p] 4B fully coalesced.
__global__ __launch_bounds__(256) void gather_kernel(
        const uint2* __restrict__ permst, const float* __restrict__ ea,
        unsigned int* __restrict__ sST, unsigned short* __restrict__ eabS) {
    const int p = blockIdx.x * 256 + threadIdx.x;   // E exact
    const uint2 v = permst[p];
    sST[p] = v.y;
    const float4* s = (const float4*)(ea + (size_t)v.x * 16);
    ushort4* d = (ushort4*)(eabS + (size_t)p * 16);
#pragma unroll
    for (int i = 0; i < 4; i++) {
        float4 f = s[i];
        d[i] = make_ushort4(f2b(f.x), f2b(f.y), f2b(f.z), f2b(f.w));
    }
}

// ---------------- per-layer node GEMM: T = h@W1a + b1, S = h@W1b ----------------
__global__ __launch_bounds__(256, 4) void node_kernel(
        const unsigned short* __restrict__ hb, const unsigned short* __restrict__ wab,
        const float* __restrict__ b1,
        unsigned short* __restrict__ Tb, unsigned short* __restrict__ Sb) {
    __shared__ __align__(16) unsigned short As[64 * KS2];
    const int t = threadIdx.x;
    const int n0 = blockIdx.x * 64;
    {
        const int m = t >> 2, q = t & 3;
        const int node = n0 + m;
        uint4* dst = (uint4*)(As + m * KS2);
        if (node < N_NODES) {
            const uint4* s = (const uint4*)(hb + (size_t)node * 128);
#pragma unroll
            for (int i = 0; i < 4; i++) dst[q * 4 + i] = s[q * 4 + i];
        } else {
            uint4 z{0, 0, 0, 0};
            for (int i = q; i < 16; i += 4) dst[i] = z;
        }
    }
    __syncthreads();

    const int wv = t >> 6, lane = t & 63, lr = lane & 15, lq = lane >> 4;
    const int cb = wv * 64;
    const f32x4 z4 = {0.f, 0.f, 0.f, 0.f};
    f32x4 acc[4][4];                     // [rt][ct]
#pragma unroll
    for (int i = 0; i < 4; i++)
#pragma unroll
        for (int j = 0; j < 4; j++) acc[i][j] = z4;

    const unsigned short* aL = As + lr * KS2 + lq * 8;
    const unsigned short* bL = wab + (size_t)(cb + lr) * KS2 + lq * 8;
#pragma unroll
    for (int kc = 0; kc < 4; kc++) {
        uint4 bA = *(const uint4*)(bL + kc * 32);
        uint4 bB = *(const uint4*)(bL + (size_t)16 * KS2 + kc * 32);
        uint4 bC = *(const uint4*)(bL + (size_t)32 * KS2 + kc * 32);
        uint4 bD = *(const uint4*)(bL + (size_t)48 * KS2 + kc * 32);
#pragma unroll
        for (int rt = 0; rt < 4; rt++) {
            uint4 a = *(const uint4*)(aL + (size_t)rt * 16 * KS2 + kc * 32);
            acc[rt][0] = mfma_bf16(a, bA, acc[rt][0]);
            acc[rt][1] = mfma_bf16(a, bB, acc[rt][1]);
            acc[rt][2] = mfma_bf16(a, bC, acc[rt][2]);
            acc[rt][3] = mfma_bf16(a, bD, acc[rt][3]);
        }
    }
#pragma unroll
    for (int ct = 0; ct < 4; ct++) {
        const int j = cb + ct * 16 + lr;
        const float bias = (j < 128) ? b1[j] : 0.f;
#pragma unroll
        for (int rt = 0; rt < 4; rt++) {
#pragma unroll
            for (int r = 0; r < 4; r++) {
                const int node = n0 + rt * 16 + lq * 4 + r;
                if (node < N_NODES) {
                    const float v = acc[rt][ct][r] + bias;
                    if (j < 128) Tb[(size_t)node * 128 + j] = f2b(v);
                    else         Sb[(size_t)node * 128 + (j - 128)] = f2b(v);
                }
            }
        }
    }
}

// ---------------- edge kernel: relu(T[tgt]+S[src]+ea@W1c) + segmented sum ----------------
// 64 edges/block processed as TWO 32-edge half-tiles over one fp32 LDS buffer
// Es[32][ESTR] (17 KB total LDS -> 8 blocks/CU, 32 waves/CU).
__global__ __launch_bounds__(256, 8) void edge_kernel(
        const unsigned short* __restrict__ eabS,
        const unsigned int* __restrict__ sST,
        const unsigned short* __restrict__ w1cp,
        const unsigned short* __restrict__ Tb, const unsigned short* __restrict__ Sb,
        float* __restrict__ aggr) {
    __shared__ __align__(16) float Es[32 * ESTR];
    __shared__ int sT[64];
    __shared__ int sS[64];

    const int t = threadIdx.x;
    const int e0 = blockIdx.x * 64;          // E = 12500*64 exact
    if (t < 64) {
        const unsigned v = sST[e0 + t];
        sT[t] = (int)(v & 0xFFFFu);
        sS[t] = (int)(v >> 16);
    }

    const int wv = t >> 6, lane = t & 63, lr = lane & 15, lq = lane >> 4;
    const int rtw = (wv >> 1) * 16;          // row-tile base within half: 0 or 16
    const int cbw = (wv & 1) * 64;           // col-block base: 0 or 64
    const f32x4 z4 = {0.f, 0.f, 0.f, 0.f};

#pragma unroll
    for (int h = 0; h < 2; h++) {
        if (h) __syncthreads();              // Es reuse: P3(h=0) done before P1(h=1)

        {   // Phase 1: wave (rtw,cbw) -> 16 edges x 64 cols, 4 MFMAs
            uint4 a = {0, 0, 0, 0};
            if (lq < 2)
                a = *(const uint4*)(eabS + (size_t)(e0 + h * 32 + rtw + lr) * 16 + lq * 8);
            f32x4 acc[4];
#pragma unroll
            for (int ct = 0; ct < 4; ct++) {
                uint4 b = *(const uint4*)(w1cp + (cbw + ct * 16 + lr) * 32 + lq * 8);
                acc[ct] = mfma_bf16(a, b, z4);
            }
#pragma unroll
            for (int ct = 0; ct < 4; ct++) {
                const int col = cbw + ct * 16 + lr;
#pragma unroll
                for (int r = 0; r < 4; r++)
                    Es[(rtw + lq * 4 + r) * ESTR + col] = acc[ct][r];
            }
        }
        __syncthreads();

        {   // Phase 2: thread -> edge m = t&31 (within half), chunks c8b + {0,8}
            const int m = t & 31;
            const int c8b = t >> 5;
            const int ge = h * 32 + m;
            const unsigned short* Trow = Tb + (size_t)sT[ge] * 128;
            const unsigned short* Srow = Sb + (size_t)sS[ge] * 128;
            float* Erow = Es + m * ESTR;
#pragma unroll
            for (int it = 0; it < 2; it++) {
                const int c0 = (c8b + it * 8) * 8;
                const uint4 tv = *(const uint4*)(Trow + c0);
                const uint4 sv = *(const uint4*)(Srow + c0);
                float tf[8] = {b2f_lo(tv.x), b2f_hi(tv.x), b2f_lo(tv.y), b2f_hi(tv.y),
                               b2f_lo(tv.z), b2f_hi(tv.z), b2f_lo(tv.w), b2f_hi(tv.w)};
                float sf[8] = {b2f_lo(sv.x), b2f_hi(sv.x), b2f_lo(sv.y), b2f_hi(sv.y),
                               b2f_lo(sv.z), b2f_hi(sv.z), b2f_lo(sv.w), b2f_hi(sv.w)};
#pragma unroll
                for (int i = 0; i < 8; i++)
                    Erow[c0 + i] = fmaxf(Erow[c0 + i] + tf[i] + sf[i], 0.f);
            }
        }
        __syncthreads();

        if ((t & 1) == h) {   // Phase 3: 128 col-threads, rows h*32 .. h*32+31
            const int c = t >> 1;
            float s = 0.f;
            int cur = sT[h * 32];
            for (int i = 0; i < 32; i++) {
                const int tg = sT[h * 32 + i];
                if (tg != cur) {
                    atomicAdd(aggr + (size_t)cur * 128 + c, s);
                    s = 0.f; cur = tg;
                }
                s += Es[i * ESTR + c];
            }
            atomicAdd(aggr + (size_t)cur * 128 + c, s);
        }
    }
}

// ---------------- update MLP + residual + LN ----------------
__global__ __launch_bounds__(256, 4) void upd_kernel(
        const unsigned short* __restrict__ hb_in, const float* __restrict__ h_in,
        const float* __restrict__ aggr, const int* __restrict__ hist,
        const unsigned short* __restrict__ u1t, const unsigned short* __restrict__ u2t,
        const float* __restrict__ b1, const float* __restrict__ bf,
        const float* __restrict__ b2,
        const float* __restrict__ g, const float* __restrict__ bet,
        float* __restrict__ h_out, unsigned short* __restrict__ hb_out) {
    __shared__ __align__(16) char smemA[64 * KSU * 2];
    __shared__ float sF[64];
    unsigned short* As = (unsigned short*)smemA;
    float* LNb = (float*)smemA;

    const int t = threadIdx.x;
    const int n0 = blockIdx.x * 64;
    {
        const int m = t >> 2, q = t & 3;
        const int node = n0 + m;
        unsigned short* row = As + m * KSU;
        if (node < N_NODES) {
            const uint4* ph = (const uint4*)(hb_in + (size_t)node * 128);
            uint4* d0 = (uint4*)row;
#pragma unroll
            for (int i = 0; i < 4; i++) d0[q * 4 + i] = ph[q * 4 + i];
            const int cntv = hist[node];
            if (q == 0) sF[m] = (cntv > 0) ? 1.f : 0.f;
            const float rden = 1.0f / fmaxf((float)cntv, 1.0f);
            const float4* pa = (const float4*)(aggr + (size_t)node * 128 + q * 32);
            ushort4* d1 = (ushort4*)(row + 128 + q * 32);
#pragma unroll
            for (int i = 0; i < 8; i++) {
                float4 v = pa[i];
                d1[i] = make_ushort4(f2b(v.x * rden), f2b(v.y * rden),
                                     f2b(v.z * rden), f2b(v.w * rden));
            }
            if (q == 0) { uint4 z{0, 0, 0, 0}; ((uint4*)(row + 256))[0] = z; }
        } else {
            if (q == 0) sF[m] = 0.f;
            uint4 z{0, 0, 0, 0};
            uint4* d = (uint4*)row;
            for (int i = q; i < 33; i += 4) d[i] = z;
        }
    }
    __syncthreads();

    const int wv = t >> 6, lane = t & 63, lr = lane & 15, lq = lane >> 4;
    const int cb = wv * 32;
    const f32x4 z4 = {0.f, 0.f, 0.f, 0.f};

    f32x4 acc[4][2];
#pragma unroll
    for (int i = 0; i < 4; i++) { acc[i][0] = z4; acc[i][1] = z4; }
    gemm_2x4<8, KSU, KSU>(As + lr * KSU + lq * 8,
                          u1t + (size_t)(cb + lr) * KSU + lq * 8, acc);
    __syncthreads();

#pragma unroll
    for (int ct = 0; ct < 2; ct++) {
        const int col = cb + ct * 16 + lr;
        const float bv = b1[col];
        const float bfv = bf[col];
#pragma unroll
        for (int rt = 0; rt < 4; rt++) {
#pragma unroll
            for (int r = 0; r < 4; r++) {
                const int ml = rt * 16 + lq * 4 + r;
                float v = fmaxf(acc[rt][ct][r] + bv + sF[ml] * bfv, 0.f);
                As[ml * KSU + col] = f2b(v);
            }
        }
    }
    __syncthreads();

    f32x4 acc2[4][2];
#pragma unroll
    for (int i = 0; i < 4; i++) { acc2[i][0] = z4; acc2[i][1] = z4; }
    gemm_2x4<4, KSU, KS2>(As + lr * KSU + lq * 8,
                          u2t + (size_t)(cb + lr) * KS2 + lq * 8, acc2);
    __syncthreads();

    // residual add into LN staging fp32 [64][132]
#pragma unroll
    for (int ct = 0; ct < 2; ct++) {
        const int col = cb + ct * 16 + lr;
        const float bv = b2[col];
#pragma unroll
        for (int rt = 0; rt < 4; rt++) {
#pragma unroll
            for (int r = 0; r < 4; r++) {
                const int ml = rt * 16 + lq * 4 + r;
                const int node = n0 + ml;
                if (node < N_NODES)
                    LNb[ml * 132 + col] = acc2[rt][ct][r] + bv + h_in[(size_t)node * 128 + col];
            }
        }
    }
    __syncthreads();

    {   // LayerNorm: 4 threads per row
        const int r = t >> 2, c0 = (t & 3) * 32;
        const int node = n0 + r;
        if (node < N_NODES) {
            float s = 0.f, ss = 0.f;
#pragma unroll
            for (int i = 0; i < 32; i++) { float v = LNb[r * 132 + c0 + i]; s += v; ss += v * v; }
            s += __shfl_xor(s, 1); ss += __shfl_xor(ss, 1);
            s += __shfl_xor(s, 2); ss += __shfl_xor(ss, 2);
            const float mu = s * (1.0f / 128.0f);
            const float var = ss * (1.0f / 128.0f) - mu * mu;
            const float rs = rsqrtf(var + 1e-5f);
#pragma unroll
            for (int i = 0; i < 32; i++) {
                const int j = c0 + i;
                float v = (LNb[r * 132 + j] - mu) * rs * g[j] + bet[j];
                h_out[(size_t)node * 128 + j] = v;
                hb_out[(size_t)node * 128 + j] = f2b(v);
            }
        }
    }
}

// ---------------- head GEMM ----------------
__global__ __launch_bounds__(256, 2) void head_kernel(
        const unsigned short* __restrict__ hb, const unsigned short* __restrict__ ht,
        const float* __restrict__ hbias, float* __restrict__ out) {
    __shared__ __align__(16) unsigned short As[64 * KS2];
    const int t = threadIdx.x;
    const int n0 = blockIdx.x * 64;
    {
        const int m = t >> 2, q = t & 3;
        const int node = n0 + m;
        uint4* dst = (uint4*)(As + m * KS2);
        if (node < N_NODES) {
            const uint4* s = (const uint4*)(hb + (size_t)node * 128);
#pragma unroll
            for (int i = 0; i < 4; i++) dst[q * 4 + i] = s[q * 4 + i];
        } else {
            uint4 z{0, 0, 0, 0};
            for (int i = q; i < 16; i += 4) dst[i] = z;
        }
    }
    __syncthreads();

    const int wv = t >> 6, lane = t & 63, lr = lane & 15, lq = lane >> 4;
    const int m0 = wv * 16;
    const f32x4 z4 = {0.f, 0.f, 0.f, 0.f};
    f32x4 acc[8];
#pragma unroll
    for (int i = 0; i < 8; i++) acc[i] = z4;
    gemm8<4, KS2>(As + (m0 + lr) * KS2 + lq * 8, ht + (size_t)lr * KS2 + lq * 8, acc);
#pragma unroll
    for (int ct = 0; ct < 8; ct++) {
        const int col = ct * 16 + lr;
        const float bv = hbias[col];
#pragma unroll
        for (int r = 0; r < 4; r++) {
            const int node = n0 + m0 + lq * 4 + r;
            if (node < N_NODES) out[(size_t)node * 128 + col] = acc[ct][r] + bv;
        }
    }
}

extern "C" void kernel_launch(void* const* d_in, const int* in_sizes, int n_in,
                              void* d_out, int out_size, void* d_ws, size_t ws_size,
                              hipStream_t stream) {
    const float* x       = (const float*)d_in[0];
    const int*   ei      = (const int*)d_in[1];
    const float* ea      = (const float*)d_in[2];
    const float* encW    = (const float*)d_in[3];
    const float* encb    = (const float*)d_in[4];
    const float* encg    = (const float*)d_in[5];
    const float* encbeta = (const float*)d_in[6];
    const float* msgW1   = (const float*)d_in[7];
    const float* msgb1   = (const float*)d_in[8];
    const float* msgW2   = (const float*)d_in[9];
    const float* msgb2   = (const float*)d_in[10];
    const float* updW1   = (const float*)d_in[11];
    const float* updb1   = (const float*)d_in[12];
    const float* updW2   = (const float*)d_in[13];
    const float* updb2   = (const float*)d_in[14];
    const float* lng     = (const float*)d_in[15];
    const float* lnbeta  = (const float*)d_in[16];
    const float* headW   = (const float*)d_in[17];
    const float* headb   = (const float*)d_in[18];

    char* w = (char*)d_ws;
    size_t off = 0;
    auto nxt = [&](size_t bytes) -> void* {
        void* p = w + off;
        off = (off + bytes + 255) & ~(size_t)255;
        return p;
    };
    float*          h     = (float*)nxt((size_t)N_NODES * 128 * 4);
    unsigned short* hb    = (unsigned short*)nxt((size_t)N_NODES * 128 * 2);
    float*          aggr  = (float*)nxt((size_t)N_NODES * 128 * 4);
    unsigned short* Tb    = (unsigned short*)nxt((size_t)N_NODES * 128 * 2);
    unsigned short* Sb    = (unsigned short*)nxt((size_t)N_NODES * 128 * 2);
    unsigned short* eabS  = (unsigned short*)nxt((size_t)N_EDGES * 16 * 2);
    unsigned int*   sST   = (unsigned int*)nxt((size_t)N_EDGES * 4);
    int*            hist  = (int*)nxt((size_t)N_NODES * 4);
    int*            incl  = (int*)nxt((size_t)N_NODES * 4);   // becomes cursor
    int*            blksum= (int*)nxt(256 * 4);
    unsigned short* wab   = (unsigned short*)nxt((size_t)NL * 256 * 136 * 2);
    unsigned short* w1cp  = (unsigned short*)nxt((size_t)NL * 128 * 32 * 2);
    unsigned short* u1t   = (unsigned short*)nxt((size_t)NL * 128 * KSU * 2);
    unsigned short* u2t   = (unsigned short*)nxt((size_t)NL * 128 * KS2 * 2);
    unsigned short* ht    = (unsigned short*)nxt((size_t)128 * KS2 * 2);
    float*          bfold = (float*)nxt((size_t)NL * 128 * 4);

    // permst (6.4 MB) aliases aggr (25.6 MB): permst's last use (gather_kernel)
    // strictly precedes aggr's first memset on the same stream.
    uint2*          permst = (uint2*)aggr;

    const int NBLK = (N_NODES + 255) / 256;   // 196
    const int PREP_N = NL * 256 * 136 + NL * 128 * 32 + NL * 128 * KSU
                     + NL * 128 * KS2 + 128 * KS2;

    hipMemsetAsync(hist, 0, (size_t)N_NODES * 4, stream);
    prep_kernel<<<(PREP_N + 255) / 256, 256, 0, stream>>>(msgW1, updW1, updW2, headW,
                                                          wab, w1cp, u1t, u2t, ht);
    prep2_kernel<<<NL * 128, 128, 0, stream>>>(msgW2, updW1, u1t);
    prep3_kernel<<<NL, 128, 0, stream>>>(msgb2, updW1, bfold);
    enc_kernel<<<25000, 256, 0, stream>>>(x, encW, encb, encg, encbeta, h, hb);
    hist_kernel<<<3125, 256, 0, stream>>>(ei + N_EDGES, hist);
    scan1_kernel<<<NBLK, 256, 0, stream>>>(hist, incl, blksum);
    scan2_kernel<<<1, 256, 0, stream>>>(blksum, NBLK);
    scan3_kernel<<<NBLK, 256, 0, stream>>>(incl, blksum, hist);
    scatterp_kernel<<<3125, 256, 0, stream>>>(ei, ei + N_EDGES, incl, permst);
    gather_kernel<<<3125, 256, 0, stream>>>(permst, ea, sST, eabS);

    for (int l = 0; l < NL; l++) {
        node_kernel<<<782, 256, 0, stream>>>(hb, wab + (size_t)l * 256 * 136,
                                             msgb1 + l * 128, Tb, Sb);
        hipMemsetAsync(aggr, 0, (size_t)N_NODES * 128 * 4, stream);
        edge_kernel<<<12500, 256, 0, stream>>>(eabS, sST,
                                               w1cp + (size_t)l * 128 * 32,
                                               Tb, Sb, aggr);
        upd_kernel<<<782, 256, 0, stream>>>(hb, h, aggr, hist,
                                            u1t + (size_t)l * 128 * KSU,
                                            u2t + (size_t)l * 128 * KS2,
                                            updb1 + l * 128, bfold + l * 128,
                                            updb2 + l * 128,
                                            lng + l * 128, lnbeta + l * 128, h, hb);
    }
    head_kernel<<<782, 256, 0, stream>>>(hb, ht, headb, (float*)d_out);
}

// Round 3
// 560.638 us; speedup vs baseline: 1.0265x; 1.0114x over previous
//
#include <hip/hip_runtime.h>
#include <hip/hip_bf16.h>
#include <stdint.h>

#define N_NODES 50000
#define N_EDGES 800000
#define NL 2

// K strides (bf16 elements)
#define KS2 136   // 128-K GEMMs: 4 k-steps, stride 136
#define KSU 264   // upd GEMM1: K=256 (8 k-steps), stride 264
#define ESTR 133  // edge_kernel fp32 LDS stride: bank=(5m+c)%32, conflict-free

typedef __bf16 bf16x8 __attribute__((ext_vector_type(8)));
typedef float f32x4 __attribute__((ext_vector_type(4)));

__device__ __forceinline__ f32x4 mfma_bf16(uint4 a, uint4 b, f32x4 c) {
    return __builtin_amdgcn_mfma_f32_16x16x32_bf16(
        __builtin_bit_cast(bf16x8, a), __builtin_bit_cast(bf16x8, b), c, 0, 0, 0);
}

__device__ __forceinline__ unsigned short f2b(float f) {
    union { float f; unsigned u; } v; v.f = f;
    unsigned r = v.u + 0x7FFFu + ((v.u >> 16) & 1u);   // RNE
    return (unsigned short)(r >> 16);
}

__device__ __forceinline__ float b2f(unsigned short u) {
    union { unsigned u; float f; } v; v.u = ((unsigned)u) << 16; return v.f;
}
__device__ __forceinline__ float b2f_lo(unsigned u) {
    union { unsigned u; float f; } v; v.u = u << 16; return v.f;
}
__device__ __forceinline__ float b2f_hi(unsigned u) {
    union { unsigned u; float f; } v; v.u = u & 0xFFFF0000u; return v.f;
}

// Per-wave 16-row x 128-col tile (head_kernel).
template<int KSTEPS, int BSTR>
__device__ __forceinline__ void gemm8(const unsigned short* aLane,
                                      const unsigned short* bLane, f32x4 acc[8]) {
#pragma unroll
    for (int kc = 0; kc < KSTEPS; kc++) {
        uint4 a = *(const uint4*)(aLane + kc * 32);
#pragma unroll
        for (int ct = 0; ct < 8; ct++) {
            uint4 b = *(const uint4*)(bLane + (size_t)ct * 16 * BSTR + kc * 32);
            acc[ct] = mfma_bf16(a, b, acc[ct]);
        }
    }
}

// Column-split wave tile: 64 rows (4 rt) x 32 cols (2 ct) per wave (upd_kernel).
template<int KSTEPS, int ASTR, int BSTR>
__device__ __forceinline__ void gemm_2x4(const unsigned short* aLane,
                                         const unsigned short* bLane,
                                         f32x4 acc[4][2]) {
#pragma unroll
    for (int kc = 0; kc < KSTEPS; kc++) {
        uint4 b0 = *(const uint4*)(bLane + kc * 32);
        uint4 b1 = *(const uint4*)(bLane + (size_t)16 * BSTR + kc * 32);
#pragma unroll
        for (int rt = 0; rt < 4; rt++) {
            uint4 a = *(const uint4*)(aLane + (size_t)rt * 16 * ASTR + kc * 32);
            acc[rt][0] = mfma_bf16(a, b0, acc[rt][0]);
            acc[rt][1] = mfma_bf16(a, b1, acc[rt][1]);
        }
    }
}

// ---------------- weight prep ----------------
__global__ void prep_kernel(const float* __restrict__ mW1,
                            const float* __restrict__ uW1, const float* __restrict__ uW2,
                            const float* __restrict__ hW,
                            unsigned short* __restrict__ wab, unsigned short* __restrict__ w1cp,
                            unsigned short* __restrict__ u1t, unsigned short* __restrict__ u2t,
                            unsigned short* __restrict__ ht) {
    int i = blockIdx.x * 256 + threadIdx.x;
    const int SA = NL * 256 * 136;
    const int SC = NL * 128 * 32;
    const int SU = NL * 128 * KSU;
    const int S3 = NL * 128 * KS2;
    const int S4 = 128 * KS2;
    if (i < SA) {
        int l = i / (256 * 136), r = i % (256 * 136), j = r / 136, k = r % 136;
        float v = 0.f;
        if (k < 128)
            v = (j < 128) ? mW1[((size_t)l * 272 + k) * 128 + j]
                          : mW1[((size_t)l * 272 + 128 + k) * 128 + (j - 128)];
        wab[i] = f2b(v);
        return;
    }
    i -= SA;
    if (i < SC) {
        int l = i / (128 * 32), r = i % (128 * 32), j = r / 32, k = r % 32;
        w1cp[i] = (k < 16) ? f2b(mW1[((size_t)l * 272 + 256 + k) * 128 + j]) : (unsigned short)0;
        return;
    }
    i -= SC;
    if (i < SU) {
        int l = i / (128 * KSU), r = i % (128 * KSU), n = r / KSU, k = r % KSU;
        if (k < 128)       u1t[i] = f2b(uW1[((size_t)l * 256 + k) * 128 + n]);
        else if (k >= 256) u1t[i] = 0;
        return;
    }
    i -= SU;
    if (i < S3) {
        int l = i / (128 * KS2), r = i % (128 * KS2), n = r / KS2, k = r % KS2;
        u2t[i] = (k < 128) ? f2b(uW2[((size_t)l * 128 + k) * 128 + n]) : (unsigned short)0;
        return;
    }
    i -= S3;
    if (i < S4) {
        int n = i / KS2, k = i % KS2;
        ht[i] = (k < 128) ? f2b(hW[(size_t)k * 128 + n]) : (unsigned short)0;
    }
}

// ---------------- prep2: u1t[l][n][128+j] = bf16( sum_c W2[l][j][c] * U1[l][128+c][n] )
__global__ void prep2_kernel(const float* __restrict__ mW2, const float* __restrict__ uW1,
                             unsigned short* __restrict__ u1t) {
    __shared__ float w2row[128];
    const int l = blockIdx.x >> 7, j = blockIdx.x & 127;
    const int n = threadIdx.x;
    w2row[n] = mW2[((size_t)l * 128 + j) * 128 + n];
    __syncthreads();
    float s = 0.f;
#pragma unroll 8
    for (int c = 0; c < 128; c++)
        s += w2row[c] * uW1[((size_t)l * 256 + 128 + c) * 128 + n];
    u1t[(size_t)l * 128 * KSU + (size_t)n * KSU + 128 + j] = f2b(s);
}

// ---------------- prep3: bfold[l][n] = sum_c b2[l][c] * U1[l][128+c][n]
__global__ void prep3_kernel(const float* __restrict__ mb2, const float* __restrict__ uW1,
                             float* __restrict__ bfold) {
    const int l = blockIdx.x;
    const int n = threadIdx.x;
    float s = 0.f;
#pragma unroll 8
    for (int c = 0; c < 128; c++)
        s += mb2[l * 128 + c] * uW1[((size_t)l * 256 + 128 + c) * 128 + n];
    bfold[l * 128 + n] = s;
}

// ---------------- encoder: relu(x@W+b) -> LN ----------------
__global__ __launch_bounds__(256) void enc_kernel(
        const float* __restrict__ x, const float* __restrict__ W,
        const float* __restrict__ b, const float* __restrict__ g, const float* __restrict__ bet,
        float* __restrict__ h, unsigned short* __restrict__ hb) {
    __shared__ float sx[64];
    __shared__ float redS[4], redSS[4];
    const int t = threadIdx.x;
    const int nb = blockIdx.x * 2;           // 2 nodes / block; 25000 blocks exact
    if (t < 64) sx[t] = x[(size_t)nb * 32 + t];
    __syncthreads();
    const int half = t >> 7, j = t & 127;
    const int node = nb + half;
    float acc = b[j];
#pragma unroll
    for (int k = 0; k < 32; k++) acc += sx[half * 32 + k] * W[k * 128 + j];
    float v = fmaxf(acc, 0.f);
    float s = v, ss = v * v;
#pragma unroll
    for (int d = 32; d > 0; d >>= 1) { s += __shfl_down(s, d); ss += __shfl_down(ss, d); }
    const int wv = t >> 6;
    if ((t & 63) == 0) { redS[wv] = s; redSS[wv] = ss; }
    __syncthreads();
    float S = redS[half * 2] + redS[half * 2 + 1];
    float SS = redSS[half * 2] + redSS[half * 2 + 1];
    float mu = S * (1.f / 128.f);
    float var = SS * (1.f / 128.f) - mu * mu;
    float rs = rsqrtf(var + 1e-5f);
    float o = (v - mu) * rs * g[j] + bet[j];
    h[(size_t)node * 128 + j] = o;
    hb[(size_t)node * 128 + j] = f2b(o);
}

// ---------------- counting sort of edges by target ----------------
__global__ void hist_kernel(const int* __restrict__ tgt, int* __restrict__ hist) {
    int i = blockIdx.x * 256 + threadIdx.x;   // E = 3125*256 exact
    atomicAdd(hist + tgt[i], 1);
}

__global__ void scan1_kernel(const int* __restrict__ hist, int* __restrict__ incl,
                             int* __restrict__ blksum) {
    __shared__ int buf[256];
    const int t = threadIdx.x;
    const int i = blockIdx.x * 256 + t;
    int v = (i < N_NODES) ? hist[i] : 0;
    buf[t] = v; __syncthreads();
#pragma unroll
    for (int d = 1; d < 256; d <<= 1) {
        int x = (t >= d) ? buf[t - d] : 0;
        __syncthreads();
        buf[t] += x;
        __syncthreads();
    }
    if (i < N_NODES) incl[i] = buf[t];
    if (t == 255) blksum[blockIdx.x] = buf[255];
}

__global__ void scan2_kernel(int* __restrict__ blksum, int nblk) {
    __shared__ int buf[256];
    const int t = threadIdx.x;
    int v = (t < nblk) ? blksum[t] : 0;
    buf[t] = v; __syncthreads();
#pragma unroll
    for (int d = 1; d < 256; d <<= 1) {
        int x = (t >= d) ? buf[t - d] : 0;
        __syncthreads();
        buf[t] += x;
        __syncthreads();
    }
    if (t < nblk) blksum[t] = buf[t];
}

__global__ void scan3_kernel(int* __restrict__ incl, const int* __restrict__ blksum,
                             const int* __restrict__ hist) {
    const int i = blockIdx.x * 256 + threadIdx.x;
    if (i >= N_NODES) return;
    const int b = blockIdx.x;
    const int base = (b > 0) ? blksum[b - 1] : 0;
    incl[i] = incl[i] + base - hist[i];
}

// ---------------- sort step 1: 8B random scatter of {edge id, packed src|tgt} ------
__global__ void scatterp_kernel(const int* __restrict__ src, const int* __restrict__ tgt,
                                int* __restrict__ cursor, uint2* __restrict__ permst) {
    const int e = blockIdx.x * 256 + threadIdx.x;   // E exact
    const int tg = tgt[e];
    const int p = atomicAdd(cursor + tg, 1);
    permst[p] = make_uint2((unsigned)e, ((unsigned)src[e] << 16) | (unsigned)tg);
}

// ---------------- sort step 2: coalesced gather + bf16 convert --------------------
__global__ __launch_bounds__(256) void gather_kernel(
        const uint2* __restrict__ permst, const float* __restrict__ ea,
        unsigned int* __restrict__ sST, unsigned short* __restrict__ eabS) {
    const int p = blockIdx.x * 256 + threadIdx.x;   // E exact
    const uint2 v = permst[p];
    sST[p] = v.y;
    const float4* s = (const float4*)(ea + (size_t)v.x * 16);
    ushort4* d = (ushort4*)(eabS + (size_t)p * 16);
#pragma unroll
    for (int i = 0; i < 4; i++) {
        float4 f = s[i];
        d[i] = make_ushort4(f2b(f.x), f2b(f.y), f2b(f.z), f2b(f.w));
    }
}

// ---------------- per-layer node GEMM: T = h@W1a + b1, S = h@W1b ----------------
__global__ __launch_bounds__(256, 4) void node_kernel(
        const unsigned short* __restrict__ hb, const unsigned short* __restrict__ wab,
        const float* __restrict__ b1,
        unsigned short* __restrict__ Tb, unsigned short* __restrict__ Sb) {
    __shared__ __align__(16) unsigned short As[64 * KS2];
    const int t = threadIdx.x;
    const int n0 = blockIdx.x * 64;
    {
        const int m = t >> 2, q = t & 3;
        const int node = n0 + m;
        uint4* dst = (uint4*)(As + m * KS2);
        if (node < N_NODES) {
            const uint4* s = (const uint4*)(hb + (size_t)node * 128);
#pragma unroll
            for (int i = 0; i < 4; i++) dst[q * 4 + i] = s[q * 4 + i];
        } else {
            uint4 z{0, 0, 0, 0};
            for (int i = q; i < 16; i += 4) dst[i] = z;
        }
    }
    __syncthreads();

    const int wv = t >> 6, lane = t & 63, lr = lane & 15, lq = lane >> 4;
    const int cb = wv * 64;
    const f32x4 z4 = {0.f, 0.f, 0.f, 0.f};
    f32x4 acc[4][4];                     // [rt][ct]
#pragma unroll
    for (int i = 0; i < 4; i++)
#pragma unroll
        for (int j = 0; j < 4; j++) acc[i][j] = z4;

    const unsigned short* aL = As + lr * KS2 + lq * 8;
    const unsigned short* bL = wab + (size_t)(cb + lr) * KS2 + lq * 8;
#pragma unroll
    for (int kc = 0; kc < 4; kc++) {
        uint4 bA = *(const uint4*)(bL + kc * 32);
        uint4 bB = *(const uint4*)(bL + (size_t)16 * KS2 + kc * 32);
        uint4 bC = *(const uint4*)(bL + (size_t)32 * KS2 + kc * 32);
        uint4 bD = *(const uint4*)(bL + (size_t)48 * KS2 + kc * 32);
#pragma unroll
        for (int rt = 0; rt < 4; rt++) {
            uint4 a = *(const uint4*)(aL + (size_t)rt * 16 * KS2 + kc * 32);
            acc[rt][0] = mfma_bf16(a, bA, acc[rt][0]);
            acc[rt][1] = mfma_bf16(a, bB, acc[rt][1]);
            acc[rt][2] = mfma_bf16(a, bC, acc[rt][2]);
            acc[rt][3] = mfma_bf16(a, bD, acc[rt][3]);
        }
    }
#pragma unroll
    for (int ct = 0; ct < 4; ct++) {
        const int j = cb + ct * 16 + lr;
        const float bias = (j < 128) ? b1[j] : 0.f;
#pragma unroll
        for (int rt = 0; rt < 4; rt++) {
#pragma unroll
            for (int r = 0; r < 4; r++) {
                const int node = n0 + rt * 16 + lq * 4 + r;
                if (node < N_NODES) {
                    const float v = acc[rt][ct][r] + bias;
                    if (j < 128) Tb[(size_t)node * 128 + j] = f2b(v);
                    else         Sb[(size_t)node * 128 + (j - 128)] = f2b(v);
                }
            }
        }
    }
}

// ---------------- edge kernel: relu(T[tgt]+S[src]+ea@W1c) + segmented sum ----------------
// 64 edges/block as TWO 32-edge half-tiles over one fp32 LDS buffer Es[32][ESTR]
// (17.9 KB LDS -> 8 blocks/CU).
//  P1: 4 waves x (16 edges x 64 cols) MFMA ea@W1c -> Es.
//  P2: 256 threads gather Tb/Sb rows (uint4), Es += T+S, relu, in place.
//  P3: segmented sum, threads t<128 (2 full waves, not 4 half-waves), one col each.
//      Segment boundaries precomputed ONCE as a 64-bit wave-uniform ballot mask
//      (SGPR) -> per-row cost is s_bitcmp + ds_read + v_add; flush reads sT only
//      when taken. Partial sum s carries across the half boundary in a register;
//      single final flush at sT[63] (fewer atomics than per-half flushing).
__global__ __launch_bounds__(256, 8) void edge_kernel(
        const unsigned short* __restrict__ eabS,
        const unsigned int* __restrict__ sST,
        const unsigned short* __restrict__ w1cp,
        const unsigned short* __restrict__ Tb, const unsigned short* __restrict__ Sb,
        float* __restrict__ aggr) {
    __shared__ __align__(16) float Es[32 * ESTR];
    __shared__ int sT[64];
    __shared__ int sS[64];

    const int t = threadIdx.x;
    const int e0 = blockIdx.x * 64;          // E = 12500*64 exact
    if (t < 64) {
        const unsigned v = sST[e0 + t];
        sT[t] = (int)(v & 0xFFFFu);
        sS[t] = (int)(v >> 16);
    }

    const int wv = t >> 6, lane = t & 63, lr = lane & 15, lq = lane >> 4;
    const int rtw = (wv >> 1) * 16;          // row-tile base within half: 0 or 16
    const int cbw = (wv & 1) * 64;           // col-block base: 0 or 64
    const f32x4 z4 = {0.f, 0.f, 0.f, 0.f};

    unsigned long long bmask = 0ULL;         // boundary mask, wave-uniform (SGPR)
    float s = 0.f;                           // P3 running segment sum (t<128)

#pragma unroll
    for (int h = 0; h < 2; h++) {
        if (h) __syncthreads();              // Es reuse: P3(h=0) done before P1(h=1)

        {   // Phase 1: wave (rtw,cbw) -> 16 edges x 64 cols, 4 MFMAs
            uint4 a = {0, 0, 0, 0};
            if (lq < 2)
                a = *(const uint4*)(eabS + (size_t)(e0 + h * 32 + rtw + lr) * 16 + lq * 8);
            f32x4 acc[4];
#pragma unroll
            for (int ct = 0; ct < 4; ct++) {
                uint4 b = *(const uint4*)(w1cp + (cbw + ct * 16 + lr) * 32 + lq * 8);
                acc[ct] = mfma_bf16(a, b, z4);
            }
#pragma unroll
            for (int ct = 0; ct < 4; ct++) {
                const int col = cbw + ct * 16 + lr;
#pragma unroll
                for (int r = 0; r < 4; r++)
                    Es[(rtw + lq * 4 + r) * ESTR + col] = acc[ct][r];
            }
        }
        __syncthreads();

        if (h == 0) {   // boundary ballot: every wave computes the same 64-bit mask
            const int l = t & 63;
            const int a = sT[l];
            const int b = (l > 0) ? sT[l - 1] : a;
            bmask = __ballot(a != b);
        }

        {   // Phase 2: thread -> edge m = t&31 (within half), chunks c8b + {0,8}
            const int m = t & 31;
            const int c8b = t >> 5;
            const int ge = h * 32 + m;
            const unsigned short* Trow = Tb + (size_t)sT[ge] * 128;
            const unsigned short* Srow = Sb + (size_t)sS[ge] * 128;
            float* Erow = Es + m * ESTR;
#pragma unroll
            for (int it = 0; it < 2; it++) {
                const int c0 = (c8b + it * 8) * 8;
                const uint4 tv = *(const uint4*)(Trow + c0);
                const uint4 sv = *(const uint4*)(Srow + c0);
                float tf[8] = {b2f_lo(tv.x), b2f_hi(tv.x), b2f_lo(tv.y), b2f_hi(tv.y),
                               b2f_lo(tv.z), b2f_hi(tv.z), b2f_lo(tv.w), b2f_hi(tv.w)};
                float sf[8] = {b2f_lo(sv.x), b2f_hi(sv.x), b2f_lo(sv.y), b2f_hi(sv.y),
                               b2f_lo(sv.z), b2f_hi(sv.z), b2f_lo(sv.w), b2f_hi(sv.w)};
#pragma unroll
                for (int i = 0; i < 8; i++)
                    Erow[c0 + i] = fmaxf(Erow[c0 + i] + tf[i] + sf[i], 0.f);
            }
        }
        __syncthreads();

        if (t < 128) {   // Phase 3: 2 full waves, col c = t, rows h*32 .. h*32+31
            const int c = t;
            const unsigned mh = (unsigned)(bmask >> (h * 32));
#pragma unroll
            for (int i = 0; i < 32; i++) {
                if (mh & (1u << i)) {        // wave-uniform scalar branch
                    atomicAdd(aggr + (size_t)sT[h * 32 + i - 1] * 128 + c, s);
                    s = 0.f;
                }
                s += Es[i * ESTR + c];
            }
        }
    }
    if (t < 128) atomicAdd(aggr + (size_t)sT[63] * 128 + t, s);
}

// ---------------- update MLP + residual + LN ----------------
__global__ __launch_bounds__(256, 4) void upd_kernel(
        const unsigned short* __restrict__ hb_in, const float* __restrict__ h_in,
        const float* __restrict__ aggr, const int* __restrict__ hist,
        const unsigned short* __restrict__ u1t, const unsigned short* __restrict__ u2t,
        const float* __restrict__ b1, const float* __restrict__ bf,
        const float* __restrict__ b2,
        const float* __restrict__ g, const float* __restrict__ bet,
        float* __restrict__ h_out, unsigned short* __restrict__ hb_out) {
    __shared__ __align__(16) char smemA[64 * KSU * 2];
    __shared__ float sF[64];
    unsigned short* As = (unsigned short*)smemA;
    float* LNb = (float*)smemA;

    const int t = threadIdx.x;
    const int n0 = blockIdx.x * 64;
    {
        const int m = t >> 2, q = t & 3;
        const int node = n0 + m;
        unsigned short* row = As + m * KSU;
        if (node < N_NODES) {
            const uint4* ph = (const uint4*)(hb_in + (size_t)node * 128);
            uint4* d0 = (uint4*)row;
#pragma unroll
            for (int i = 0; i < 4; i++) d0[q * 4 + i] = ph[q * 4 + i];
            const int cntv = hist[node];
            if (q == 0) sF[m] = (cntv > 0) ? 1.f : 0.f;
            const float rden = 1.0f / fmaxf((float)cntv, 1.0f);
            const float4* pa = (const float4*)(aggr + (size_t)node * 128 + q * 32);
            ushort4* d1 = (ushort4*)(row + 128 + q * 32);
#pragma unroll
            for (int i = 0; i < 8; i++) {
                float4 v = pa[i];
                d1[i] = make_ushort4(f2b(v.x * rden), f2b(v.y * rden),
                                     f2b(v.z * rden), f2b(v.w * rden));
            }
            if (q == 0) { uint4 z{0, 0, 0, 0}; ((uint4*)(row + 256))[0] = z; }
        } else {
            if (q == 0) sF[m] = 0.f;
            uint4 z{0, 0, 0, 0};
            uint4* d = (uint4*)row;
            for (int i = q; i < 33; i += 4) d[i] = z;
        }
    }
    __syncthreads();

    const int wv = t >> 6, lane = t & 63, lr = lane & 15, lq = lane >> 4;
    const int cb = wv * 32;
    const f32x4 z4 = {0.f, 0.f, 0.f, 0.f};

    f32x4 acc[4][2];
#pragma unroll
    for (int i = 0; i < 4; i++) { acc[i][0] = z4; acc[i][1] = z4; }
    gemm_2x4<8, KSU, KSU>(As + lr * KSU + lq * 8,
                          u1t + (size_t)(cb + lr) * KSU + lq * 8, acc);
    __syncthreads();

#pragma unroll
    for (int ct = 0; ct < 2; ct++) {
        const int col = cb + ct * 16 + lr;
        const float bv = b1[col];
        const float bfv = bf[col];
#pragma unroll
        for (int rt = 0; rt < 4; rt++) {
#pragma unroll
            for (int r = 0; r < 4; r++) {
                const int ml = rt * 16 + lq * 4 + r;
                float v = fmaxf(acc[rt][ct][r] + bv + sF[ml] * bfv, 0.f);
                As[ml * KSU + col] = f2b(v);
            }
        }
    }
    __syncthreads();

    f32x4 acc2[4][2];
#pragma unroll
    for (int i = 0; i < 4; i++) { acc2[i][0] = z4; acc2[i][1] = z4; }
    gemm_2x4<4, KSU, KS2>(As + lr * KSU + lq * 8,
                          u2t + (size_t)(cb + lr) * KS2 + lq * 8, acc2);
    __syncthreads();

    // residual add into LN staging fp32 [64][132]
#pragma unroll
    for (int ct = 0; ct < 2; ct++) {
        const int col = cb + ct * 16 + lr;
        const float bv = b2[col];
#pragma unroll
        for (int rt = 0; rt < 4; rt++) {
#pragma unroll
            for (int r = 0; r < 4; r++) {
                const int ml = rt * 16 + lq * 4 + r;
                const int node = n0 + ml;
                if (node < N_NODES)
                    LNb[ml * 132 + col] = acc2[rt][ct][r] + bv + h_in[(size_t)node * 128 + col];
            }
        }
    }
    __syncthreads();

    {   // LayerNorm: 4 threads per row
        const int r = t >> 2, c0 = (t & 3) * 32;
        const int node = n0 + r;
        if (node < N_NODES) {
            float s = 0.f, ss = 0.f;
#pragma unroll
            for (int i = 0; i < 32; i++) { float v = LNb[r * 132 + c0 + i]; s += v; ss += v * v; }
            s += __shfl_xor(s, 1); ss += __shfl_xor(ss, 1);
            s += __shfl_xor(s, 2); ss += __shfl_xor(ss, 2);
            const float mu = s * (1.0f / 128.0f);
            const float var = ss * (1.0f / 128.0f) - mu * mu;
            const float rs = rsqrtf(var + 1e-5f);
#pragma unroll
            for (int i = 0; i < 32; i++) {
                const int j = c0 + i;
                float v = (LNb[r * 132 + j] - mu) * rs * g[j] + bet[j];
                h_out[(size_t)node * 128 + j] = v;
                hb_out[(size_t)node * 128 + j] = f2b(v);
            }
        }
    }
}

// ---------------- head GEMM ----------------
__global__ __launch_bounds__(256, 2) void head_kernel(
        const unsigned short* __restrict__ hb, const unsigned short* __restrict__ ht,
        const float* __restrict__ hbias, float* __restrict__ out) {
    __shared__ __align__(16) unsigned short As[64 * KS2];
    const int t = threadIdx.x;
    const int n0 = blockIdx.x * 64;
    {
        const int m = t >> 2, q = t & 3;
        const int node = n0 + m;
        uint4* dst = (uint4*)(As + m * KS2);
        if (node < N_NODES) {
            const uint4* s = (const uint4*)(hb + (size_t)node * 128);
#pragma unroll
            for (int i = 0; i < 4; i++) dst[q * 4 + i] = s[q * 4 + i];
        } else {
            uint4 z{0, 0, 0, 0};
            for (int i = q; i < 16; i += 4) dst[i] = z;
        }
    }
    __syncthreads();

    const int wv = t >> 6, lane = t & 63, lr = lane & 15, lq = lane >> 4;
    const int m0 = wv * 16;
    const f32x4 z4 = {0.f, 0.f, 0.f, 0.f};
    f32x4 acc[8];
#pragma unroll
    for (int i = 0; i < 8; i++) acc[i] = z4;
    gemm8<4, KS2>(As + (m0 + lr) * KS2 + lq * 8, ht + (size_t)lr * KS2 + lq * 8, acc);
#pragma unroll
    for (int ct = 0; ct < 8; ct++) {
        const int col = ct * 16 + lr;
        const float bv = hbias[col];
#pragma unroll
        for (int r = 0; r < 4; r++) {
            const int node = n0 + m0 + lq * 4 + r;
            if (node < N_NODES) out[(size_t)node * 128 + col] = acc[ct][r] + bv;
        }
    }
}

extern "C" void kernel_launch(void* const* d_in, const int* in_sizes, int n_in,
                              void* d_out, int out_size, void* d_ws, size_t ws_size,
                              hipStream_t stream) {
    const float* x       = (const float*)d_in[0];
    const int*   ei      = (const int*)d_in[1];
    const float* ea      = (const float*)d_in[2];
    const float* encW    = (const float*)d_in[3];
    const float* encb    = (const float*)d_in[4];
    const float* encg    = (const float*)d_in[5];
    const float* encbeta = (const float*)d_in[6];
    const float* msgW1   = (const float*)d_in[7];
    const float* msgb1   = (const float*)d_in[8];
    const float* msgW2   = (const float*)d_in[9];
    const float* msgb2   = (const float*)d_in[10];
    const float* updW1   = (const float*)d_in[11];
    const float* updb1   = (const float*)d_in[12];
    const float* updW2   = (const float*)d_in[13];
    const float* updb2   = (const float*)d_in[14];
    const float* lng     = (const float*)d_in[15];
    const float* lnbeta  = (const float*)d_in[16];
    const float* headW   = (const float*)d_in[17];
    const float* headb   = (const float*)d_in[18];

    char* w = (char*)d_ws;
    size_t off = 0;
    auto nxt = [&](size_t bytes) -> void* {
        void* p = w + off;
        off = (off + bytes + 255) & ~(size_t)255;
        return p;
    };
    float*          h     = (float*)nxt((size_t)N_NODES * 128 * 4);
    unsigned short* hb    = (unsigned short*)nxt((size_t)N_NODES * 128 * 2);
    float*          aggr  = (float*)nxt((size_t)N_NODES * 128 * 4);
    unsigned short* Tb    = (unsigned short*)nxt((size_t)N_NODES * 128 * 2);
    unsigned short* Sb    = (unsigned short*)nxt((size_t)N_NODES * 128 * 2);
    unsigned short* eabS  = (unsigned short*)nxt((size_t)N_EDGES * 16 * 2);
    unsigned int*   sST   = (unsigned int*)nxt((size_t)N_EDGES * 4);
    int*            hist  = (int*)nxt((size_t)N_NODES * 4);
    int*            incl  = (int*)nxt((size_t)N_NODES * 4);   // becomes cursor
    int*            blksum= (int*)nxt(256 * 4);
    unsigned short* wab   = (unsigned short*)nxt((size_t)NL * 256 * 136 * 2);
    unsigned short* w1cp  = (unsigned short*)nxt((size_t)NL * 128 * 32 * 2);
    unsigned short* u1t   = (unsigned short*)nxt((size_t)NL * 128 * KSU * 2);
    unsigned short* u2t   = (unsigned short*)nxt((size_t)NL * 128 * KS2 * 2);
    unsigned short* ht    = (unsigned short*)nxt((size_t)128 * KS2 * 2);
    float*          bfold = (float*)nxt((size_t)NL * 128 * 4);

    // permst (6.4 MB) aliases aggr (25.6 MB): permst's last use (gather_kernel)
    // strictly precedes aggr's first memset on the same stream.
    uint2*          permst = (uint2*)aggr;

    const int NBLK = (N_NODES + 255) / 256;   // 196
    const int PREP_N = NL * 256 * 136 + NL * 128 * 32 + NL * 128 * KSU
                     + NL * 128 * KS2 + 128 * KS2;

    hipMemsetAsync(hist, 0, (size_t)N_NODES * 4, stream);
    prep_kernel<<<(PREP_N + 255) / 256, 256, 0, stream>>>(msgW1, updW1, updW2, headW,
                                                          wab, w1cp, u1t, u2t, ht);
    prep2_kernel<<<NL * 128, 128, 0, stream>>>(msgW2, updW1, u1t);
    prep3_kernel<<<NL, 128, 0, stream>>>(msgb2, updW1, bfold);
    enc_kernel<<<25000, 256, 0, stream>>>(x, encW, encb, encg, encbeta, h, hb);
    hist_kernel<<<3125, 256, 0, stream>>>(ei + N_EDGES, hist);
    scan1_kernel<<<NBLK, 256, 0, stream>>>(hist, incl, blksum);
    scan2_kernel<<<1, 256, 0, stream>>>(blksum, NBLK);
    scan3_kernel<<<NBLK, 256, 0, stream>>>(incl, blksum, hist);
    scatterp_kernel<<<3125, 256, 0, stream>>>(ei, ei + N_EDGES, incl, permst);
    gather_kernel<<<3125, 256, 0, stream>>>(permst, ea, sST, eabS);

    for (int l = 0; l < NL; l++) {
        node_kernel<<<782, 256, 0, stream>>>(hb, wab + (size_t)l * 256 * 136,
                                             msgb1 + l * 128, Tb, Sb);
        hipMemsetAsync(aggr, 0, (size_t)N_NODES * 128 * 4, stream);
        edge_kernel<<<12500, 256, 0, stream>>>(eabS, sST,
                                               w1cp + (size_t)l * 128 * 32,
                                               Tb, Sb, aggr);
        upd_kernel<<<782, 256, 0, stream>>>(hb, h, aggr, hist,
                                            u1t + (size_t)l * 128 * KSU,
                                            u2t + (size_t)l * 128 * KS2,
                                            updb1 + l * 128, bfold + l * 128,
                                            updb2 + l * 128,
                                            lng + l * 128, lnbeta + l * 128, h, hb);
    }
    head_kernel<<<782, 256, 0, stream>>>(hb, ht, headb, (float*)d_out);
}

// Round 4
// 558.288 us; speedup vs baseline: 1.0309x; 1.0042x over previous
//
#include <hip/hip_runtime.h>
#include <hip/hip_bf16.h>
#include <stdint.h>

#define N_NODES 50000
#define N_EDGES 800000
#define NL 2

// K strides (bf16 elements)
#define KS2 136   // 128-K GEMMs: 4 k-steps, stride 136
#define KSU 264   // upd GEMM1: K=256 (8 k-steps), stride 264
#define ESTR 133  // edge_kernel fp32 LDS stride: bank=(5m+c)%32, conflict-free

typedef __bf16 bf16x8 __attribute__((ext_vector_type(8)));
typedef float f32x4 __attribute__((ext_vector_type(4)));

__device__ __forceinline__ f32x4 mfma_bf16(uint4 a, uint4 b, f32x4 c) {
    return __builtin_amdgcn_mfma_f32_16x16x32_bf16(
        __builtin_bit_cast(bf16x8, a), __builtin_bit_cast(bf16x8, b), c, 0, 0, 0);
}

__device__ __forceinline__ unsigned short f2b(float f) {
    union { float f; unsigned u; } v; v.f = f;
    unsigned r = v.u + 0x7FFFu + ((v.u >> 16) & 1u);   // RNE
    return (unsigned short)(r >> 16);
}

__device__ __forceinline__ float b2f(unsigned short u) {
    union { unsigned u; float f; } v; v.u = ((unsigned)u) << 16; return v.f;
}
__device__ __forceinline__ float b2f_lo(unsigned u) {
    union { unsigned u; float f; } v; v.u = u << 16; return v.f;
}
__device__ __forceinline__ float b2f_hi(unsigned u) {
    union { unsigned u; float f; } v; v.u = u & 0xFFFF0000u; return v.f;
}

// Per-wave 16-row x 128-col tile (head_kernel).
template<int KSTEPS, int BSTR>
__device__ __forceinline__ void gemm8(const unsigned short* aLane,
                                      const unsigned short* bLane, f32x4 acc[8]) {
#pragma unroll
    for (int kc = 0; kc < KSTEPS; kc++) {
        uint4 a = *(const uint4*)(aLane + kc * 32);
#pragma unroll
        for (int ct = 0; ct < 8; ct++) {
            uint4 b = *(const uint4*)(bLane + (size_t)ct * 16 * BSTR + kc * 32);
            acc[ct] = mfma_bf16(a, b, acc[ct]);
        }
    }
}

// Column-split wave tile: 64 rows (4 rt) x 32 cols (2 ct) per wave (upd_kernel).
template<int KSTEPS, int ASTR, int BSTR>
__device__ __forceinline__ void gemm_2x4(const unsigned short* aLane,
                                         const unsigned short* bLane,
                                         f32x4 acc[4][2]) {
#pragma unroll
    for (int kc = 0; kc < KSTEPS; kc++) {
        uint4 b0 = *(const uint4*)(bLane + kc * 32);
        uint4 b1 = *(const uint4*)(bLane + (size_t)16 * BSTR + kc * 32);
#pragma unroll
        for (int rt = 0; rt < 4; rt++) {
            uint4 a = *(const uint4*)(aLane + (size_t)rt * 16 * ASTR + kc * 32);
            acc[rt][0] = mfma_bf16(a, b0, acc[rt][0]);
            acc[rt][1] = mfma_bf16(a, b1, acc[rt][1]);
        }
    }
}

// ---------------- weight prep ----------------
__global__ void prep_kernel(const float* __restrict__ mW1,
                            const float* __restrict__ uW1, const float* __restrict__ uW2,
                            const float* __restrict__ hW,
                            unsigned short* __restrict__ wab, unsigned short* __restrict__ w1cp,
                            unsigned short* __restrict__ u1t, unsigned short* __restrict__ u2t,
                            unsigned short* __restrict__ ht) {
    int i = blockIdx.x * 256 + threadIdx.x;
    const int SA = NL * 256 * 136;
    const int SC = NL * 128 * 32;
    const int SU = NL * 128 * KSU;
    const int S3 = NL * 128 * KS2;
    const int S4 = 128 * KS2;
    if (i < SA) {
        int l = i / (256 * 136), r = i % (256 * 136), j = r / 136, k = r % 136;
        float v = 0.f;
        if (k < 128)
            v = (j < 128) ? mW1[((size_t)l * 272 + k) * 128 + j]
                          : mW1[((size_t)l * 272 + 128 + k) * 128 + (j - 128)];
        wab[i] = f2b(v);
        return;
    }
    i -= SA;
    if (i < SC) {
        int l = i / (128 * 32), r = i % (128 * 32), j = r / 32, k = r % 32;
        w1cp[i] = (k < 16) ? f2b(mW1[((size_t)l * 272 + 256 + k) * 128 + j]) : (unsigned short)0;
        return;
    }
    i -= SC;
    if (i < SU) {
        int l = i / (128 * KSU), r = i % (128 * KSU), n = r / KSU, k = r % KSU;
        if (k < 128)       u1t[i] = f2b(uW1[((size_t)l * 256 + k) * 128 + n]);
        else if (k >= 256) u1t[i] = 0;
        return;
    }
    i -= SU;
    if (i < S3) {
        int l = i / (128 * KS2), r = i % (128 * KS2), n = r / KS2, k = r % KS2;
        u2t[i] = (k < 128) ? f2b(uW2[((size_t)l * 128 + k) * 128 + n]) : (unsigned short)0;
        return;
    }
    i -= S3;
    if (i < S4) {
        int n = i / KS2, k = i % KS2;
        ht[i] = (k < 128) ? f2b(hW[(size_t)k * 128 + n]) : (unsigned short)0;
    }
}

// ---------------- prep2: u1t[l][n][128+j] = bf16( sum_c W2[l][j][c] * U1[l][128+c][n] )
__global__ void prep2_kernel(const float* __restrict__ mW2, const float* __restrict__ uW1,
                             unsigned short* __restrict__ u1t) {
    __shared__ float w2row[128];
    const int l = blockIdx.x >> 7, j = blockIdx.x & 127;
    const int n = threadIdx.x;
    w2row[n] = mW2[((size_t)l * 128 + j) * 128 + n];
    __syncthreads();
    float s = 0.f;
#pragma unroll 8
    for (int c = 0; c < 128; c++)
        s += w2row[c] * uW1[((size_t)l * 256 + 128 + c) * 128 + n];
    u1t[(size_t)l * 128 * KSU + (size_t)n * KSU + 128 + j] = f2b(s);
}

// ---------------- prep3: bfold[l][n] = sum_c b2[l][c] * U1[l][128+c][n]
__global__ void prep3_kernel(const float* __restrict__ mb2, const float* __restrict__ uW1,
                             float* __restrict__ bfold) {
    const int l = blockIdx.x;
    const int n = threadIdx.x;
    float s = 0.f;
#pragma unroll 8
    for (int c = 0; c < 128; c++)
        s += mb2[l * 128 + c] * uW1[((size_t)l * 256 + 128 + c) * 128 + n];
    bfold[l * 128 + n] = s;
}

// ---------------- encoder: relu(x@W+b) -> LN ----------------
__global__ __launch_bounds__(256) void enc_kernel(
        const float* __restrict__ x, const float* __restrict__ W,
        const float* __restrict__ b, const float* __restrict__ g, const float* __restrict__ bet,
        float* __restrict__ h, unsigned short* __restrict__ hb) {
    __shared__ float sx[64];
    __shared__ float redS[4], redSS[4];
    const int t = threadIdx.x;
    const int nb = blockIdx.x * 2;           // 2 nodes / block; 25000 blocks exact
    if (t < 64) sx[t] = x[(size_t)nb * 32 + t];
    __syncthreads();
    const int half = t >> 7, j = t & 127;
    const int node = nb + half;
    float acc = b[j];
#pragma unroll
    for (int k = 0; k < 32; k++) acc += sx[half * 32 + k] * W[k * 128 + j];
    float v = fmaxf(acc, 0.f);
    float s = v, ss = v * v;
#pragma unroll
    for (int d = 32; d > 0; d >>= 1) { s += __shfl_down(s, d); ss += __shfl_down(ss, d); }
    const int wv = t >> 6;
    if ((t & 63) == 0) { redS[wv] = s; redSS[wv] = ss; }
    __syncthreads();
    float S = redS[half * 2] + redS[half * 2 + 1];
    float SS = redSS[half * 2] + redSS[half * 2 + 1];
    float mu = S * (1.f / 128.f);
    float var = SS * (1.f / 128.f) - mu * mu;
    float rs = rsqrtf(var + 1e-5f);
    float o = (v - mu) * rs * g[j] + bet[j];
    h[(size_t)node * 128 + j] = o;
    hb[(size_t)node * 128 + j] = f2b(o);
}

// ---------------- counting sort of edges by target ----------------
__global__ void hist_kernel(const int* __restrict__ tgt, int* __restrict__ hist) {
    int i = blockIdx.x * 256 + threadIdx.x;   // E = 3125*256 exact
    atomicAdd(hist + tgt[i], 1);
}

__global__ void scan1_kernel(const int* __restrict__ hist, int* __restrict__ incl,
                             int* __restrict__ blksum) {
    __shared__ int buf[256];
    const int t = threadIdx.x;
    const int i = blockIdx.x * 256 + t;
    int v = (i < N_NODES) ? hist[i] : 0;
    buf[t] = v; __syncthreads();
#pragma unroll
    for (int d = 1; d < 256; d <<= 1) {
        int x = (t >= d) ? buf[t - d] : 0;
        __syncthreads();
        buf[t] += x;
        __syncthreads();
    }
    if (i < N_NODES) incl[i] = buf[t];
    if (t == 255) blksum[blockIdx.x] = buf[255];
}

__global__ void scan2_kernel(int* __restrict__ blksum, int nblk) {
    __shared__ int buf[256];
    const int t = threadIdx.x;
    int v = (t < nblk) ? blksum[t] : 0;
    buf[t] = v; __syncthreads();
#pragma unroll
    for (int d = 1; d < 256; d <<= 1) {
        int x = (t >= d) ? buf[t - d] : 0;
        __syncthreads();
        buf[t] += x;
        __syncthreads();
    }
    if (t < nblk) blksum[t] = buf[t];
}

__global__ void scan3_kernel(int* __restrict__ incl, const int* __restrict__ blksum,
                             const int* __restrict__ hist) {
    const int i = blockIdx.x * 256 + threadIdx.x;
    if (i >= N_NODES) return;
    const int b = blockIdx.x;
    const int base = (b > 0) ? blksum[b - 1] : 0;
    incl[i] = incl[i] + base - hist[i];
}

// ---------------- sort step 1: 8B random scatter of {edge id, packed src|tgt} ------
__global__ void scatterp_kernel(const int* __restrict__ src, const int* __restrict__ tgt,
                                int* __restrict__ cursor, uint2* __restrict__ permst) {
    const int e = blockIdx.x * 256 + threadIdx.x;   // E exact
    const int tg = tgt[e];
    const int p = atomicAdd(cursor + tg, 1);
    permst[p] = make_uint2((unsigned)e, ((unsigned)src[e] << 16) | (unsigned)tg);
}

// ---------------- sort step 2: coalesced gather + bf16 convert --------------------
__global__ __launch_bounds__(256) void gather_kernel(
        const uint2* __restrict__ permst, const float* __restrict__ ea,
        unsigned int* __restrict__ sST, unsigned short* __restrict__ eabS) {
    const int p = blockIdx.x * 256 + threadIdx.x;   // E exact
    const uint2 v = permst[p];
    sST[p] = v.y;
    const float4* s = (const float4*)(ea + (size_t)v.x * 16);
    ushort4* d = (ushort4*)(eabS + (size_t)p * 16);
#pragma unroll
    for (int i = 0; i < 4; i++) {
        float4 f = s[i];
        d[i] = make_ushort4(f2b(f.x), f2b(f.y), f2b(f.z), f2b(f.w));
    }
}

// ---------------- per-layer node GEMM: T = h@W1a + b1, S = h@W1b ----------------
__global__ __launch_bounds__(256, 4) void node_kernel(
        const unsigned short* __restrict__ hb, const unsigned short* __restrict__ wab,
        const float* __restrict__ b1,
        unsigned short* __restrict__ Tb, unsigned short* __restrict__ Sb) {
    __shared__ __align__(16) unsigned short As[64 * KS2];
    const int t = threadIdx.x;
    const int n0 = blockIdx.x * 64;
    {
        const int m = t >> 2, q = t & 3;
        const int node = n0 + m;
        uint4* dst = (uint4*)(As + m * KS2);
        if (node < N_NODES) {
            const uint4* s = (const uint4*)(hb + (size_t)node * 128);
#pragma unroll
            for (int i = 0; i < 4; i++) dst[q * 4 + i] = s[q * 4 + i];
        } else {
            uint4 z{0, 0, 0, 0};
            for (int i = q; i < 16; i += 4) dst[i] = z;
        }
    }
    __syncthreads();

    const int wv = t >> 6, lane = t & 63, lr = lane & 15, lq = lane >> 4;
    const int cb = wv * 64;
    const f32x4 z4 = {0.f, 0.f, 0.f, 0.f};
    f32x4 acc[4][4];                     // [rt][ct]
#pragma unroll
    for (int i = 0; i < 4; i++)
#pragma unroll
        for (int j = 0; j < 4; j++) acc[i][j] = z4;

    const unsigned short* aL = As + lr * KS2 + lq * 8;
    const unsigned short* bL = wab + (size_t)(cb + lr) * KS2 + lq * 8;
#pragma unroll
    for (int kc = 0; kc < 4; kc++) {
        uint4 bA = *(const uint4*)(bL + kc * 32);
        uint4 bB = *(const uint4*)(bL + (size_t)16 * KS2 + kc * 32);
        uint4 bC = *(const uint4*)(bL + (size_t)32 * KS2 + kc * 32);
        uint4 bD = *(const uint4*)(bL + (size_t)48 * KS2 + kc * 32);
#pragma unroll
        for (int rt = 0; rt < 4; rt++) {
            uint4 a = *(const uint4*)(aL + (size_t)rt * 16 * KS2 + kc * 32);
            acc[rt][0] = mfma_bf16(a, bA, acc[rt][0]);
            acc[rt][1] = mfma_bf16(a, bB, acc[rt][1]);
            acc[rt][2] = mfma_bf16(a, bC, acc[rt][2]);
            acc[rt][3] = mfma_bf16(a, bD, acc[rt][3]);
        }
    }
#pragma unroll
    for (int ct = 0; ct < 4; ct++) {
        const int j = cb + ct * 16 + lr;
        const float bias = (j < 128) ? b1[j] : 0.f;
#pragma unroll
        for (int rt = 0; rt < 4; rt++) {
#pragma unroll
            for (int r = 0; r < 4; r++) {
                const int node = n0 + rt * 16 + lq * 4 + r;
                if (node < N_NODES) {
                    const float v = acc[rt][ct][r] + bias;
                    if (j < 128) Tb[(size_t)node * 128 + j] = f2b(v);
                    else         Sb[(size_t)node * 128 + (j - 128)] = f2b(v);
                }
            }
        }
    }
}

// ---------------- edge kernel: relu(T[tgt]+S[src]+ea@W1c) + segmented sum ----------------
// 64 edges/block as TWO 32-edge half-tiles over one fp32 LDS buffer Es[32][ESTR]
// (17.9 KB LDS -> 8 blocks/CU).
//  P1: 4 waves x (16 edges x 64 cols) MFMA ea@W1c -> Es.
//  P2: 256 threads gather Tb/Sb rows (uint4), Es += T+S, relu, in place.
//  P3: segmented sum, threads t<128, one col each; boundaries as 64-bit wave-uniform
//      ballot mask (SGPR). ATOMIC-MINIMIZED: edges sorted by target => a segment not
//      touching row 0 or row 63 is entirely block-private (aggr pre-zeroed, no other
//      writer) -> plain coalesced store. Only the FIRST flush (may continue prev
//      block) and the FINAL flush (may continue next block) use atomicAdd.
//      ~8M atomics/layer -> ~3.2M.
__global__ __launch_bounds__(256, 8) void edge_kernel(
        const unsigned short* __restrict__ eabS,
        const unsigned int* __restrict__ sST,
        const unsigned short* __restrict__ w1cp,
        const unsigned short* __restrict__ Tb, const unsigned short* __restrict__ Sb,
        float* __restrict__ aggr) {
    __shared__ __align__(16) float Es[32 * ESTR];
    __shared__ int sT[64];
    __shared__ int sS[64];

    const int t = threadIdx.x;
    const int e0 = blockIdx.x * 64;          // E = 12500*64 exact
    if (t < 64) {
        const unsigned v = sST[e0 + t];
        sT[t] = (int)(v & 0xFFFFu);
        sS[t] = (int)(v >> 16);
    }

    const int wv = t >> 6, lane = t & 63, lr = lane & 15, lq = lane >> 4;
    const int rtw = (wv >> 1) * 16;          // row-tile base within half: 0 or 16
    const int cbw = (wv & 1) * 64;           // col-block base: 0 or 64
    const f32x4 z4 = {0.f, 0.f, 0.f, 0.f};

    unsigned long long bmask = 0ULL;         // boundary mask, wave-uniform (SGPR)
    float s = 0.f;                           // P3 running segment sum (t<128)
    bool first = true;                       // first flush -> atomic; interior -> store

#pragma unroll
    for (int h = 0; h < 2; h++) {
        if (h) __syncthreads();              // Es reuse: P3(h=0) done before P1(h=1)

        {   // Phase 1: wave (rtw,cbw) -> 16 edges x 64 cols, 4 MFMAs
            uint4 a = {0, 0, 0, 0};
            if (lq < 2)
                a = *(const uint4*)(eabS + (size_t)(e0 + h * 32 + rtw + lr) * 16 + lq * 8);
            f32x4 acc[4];
#pragma unroll
            for (int ct = 0; ct < 4; ct++) {
                uint4 b = *(const uint4*)(w1cp + (cbw + ct * 16 + lr) * 32 + lq * 8);
                acc[ct] = mfma_bf16(a, b, z4);
            }
#pragma unroll
            for (int ct = 0; ct < 4; ct++) {
                const int col = cbw + ct * 16 + lr;
#pragma unroll
                for (int r = 0; r < 4; r++)
                    Es[(rtw + lq * 4 + r) * ESTR + col] = acc[ct][r];
            }
        }
        __syncthreads();

        if (h == 0) {   // boundary ballot: every wave computes the same 64-bit mask
            const int l = t & 63;
            const int a = sT[l];
            const int b = (l > 0) ? sT[l - 1] : a;
            bmask = __ballot(a != b);
        }

        {   // Phase 2: thread -> edge m = t&31 (within half), chunks c8b + {0,8}
            const int m = t & 31;
            const int c8b = t >> 5;
            const int ge = h * 32 + m;
            const unsigned short* Trow = Tb + (size_t)sT[ge] * 128;
            const unsigned short* Srow = Sb + (size_t)sS[ge] * 128;
            float* Erow = Es + m * ESTR;
#pragma unroll
            for (int it = 0; it < 2; it++) {
                const int c0 = (c8b + it * 8) * 8;
                const uint4 tv = *(const uint4*)(Trow + c0);
                const uint4 sv = *(const uint4*)(Srow + c0);
                float tf[8] = {b2f_lo(tv.x), b2f_hi(tv.x), b2f_lo(tv.y), b2f_hi(tv.y),
                               b2f_lo(tv.z), b2f_hi(tv.z), b2f_lo(tv.w), b2f_hi(tv.w)};
                float sf[8] = {b2f_lo(sv.x), b2f_hi(sv.x), b2f_lo(sv.y), b2f_hi(sv.y),
                               b2f_lo(sv.z), b2f_hi(sv.z), b2f_lo(sv.w), b2f_hi(sv.w)};
#pragma unroll
                for (int i = 0; i < 8; i++)
                    Erow[c0 + i] = fmaxf(Erow[c0 + i] + tf[i] + sf[i], 0.f);
            }
        }
        __syncthreads();

        if (t < 128) {   // Phase 3: 2 full waves, col c = t, rows h*32 .. h*32+31
            const int c = t;
            const unsigned mh = (unsigned)(bmask >> (h * 32));
#pragma unroll
            for (int i = 0; i < 32; i++) {
                if (mh & (1u << i)) {        // wave-uniform scalar branch
                    float* dst = aggr + (size_t)sT[h * 32 + i - 1] * 128 + c;
                    if (first) { atomicAdd(dst, s); first = false; }
                    else       { *dst = s; }          // block-private segment
                    s = 0.f;
                }
                s += Es[i * ESTR + c];
            }
        }
    }
    if (t < 128) atomicAdd(aggr + (size_t)sT[63] * 128 + t, s);   // may span blocks
}

// ---------------- update MLP + residual + LN ----------------
__global__ __launch_bounds__(256, 4) void upd_kernel(
        const unsigned short* __restrict__ hb_in, const float* __restrict__ h_in,
        const float* __restrict__ aggr, const int* __restrict__ hist,
        const unsigned short* __restrict__ u1t, const unsigned short* __restrict__ u2t,
        const float* __restrict__ b1, const float* __restrict__ bf,
        const float* __restrict__ b2,
        const float* __restrict__ g, const float* __restrict__ bet,
        float* __restrict__ h_out, unsigned short* __restrict__ hb_out) {
    __shared__ __align__(16) char smemA[64 * KSU * 2];
    __shared__ float sF[64];
    unsigned short* As = (unsigned short*)smemA;
    float* LNb = (float*)smemA;

    const int t = threadIdx.x;
    const int n0 = blockIdx.x * 64;
    {
        const int m = t >> 2, q = t & 3;
        const int node = n0 + m;
        unsigned short* row = As + m * KSU;
        if (node < N_NODES) {
            const uint4* ph = (const uint4*)(hb_in + (size_t)node * 128);
            uint4* d0 = (uint4*)row;
#pragma unroll
            for (int i = 0; i < 4; i++) d0[q * 4 + i] = ph[q * 4 + i];
            const int cntv = hist[node];
            if (q == 0) sF[m] = (cntv > 0) ? 1.f : 0.f;
            const float rden = 1.0f / fmaxf((float)cntv, 1.0f);
            const float4* pa = (const float4*)(aggr + (size_t)node * 128 + q * 32);
            ushort4* d1 = (ushort4*)(row + 128 + q * 32);
#pragma unroll
            for (int i = 0; i < 8; i++) {
                float4 v = pa[i];
                d1[i] = make_ushort4(f2b(v.x * rden), f2b(v.y * rden),
                                     f2b(v.z * rden), f2b(v.w * rden));
            }
            if (q == 0) { uint4 z{0, 0, 0, 0}; ((uint4*)(row + 256))[0] = z; }
        } else {
            if (q == 0) sF[m] = 0.f;
            uint4 z{0, 0, 0, 0};
            uint4* d = (uint4*)row;
            for (int i = q; i < 33; i += 4) d[i] = z;
        }
    }
    __syncthreads();

    const int wv = t >> 6, lane = t & 63, lr = lane & 15, lq = lane >> 4;
    const int cb = wv * 32;
    const f32x4 z4 = {0.f, 0.f, 0.f, 0.f};

    f32x4 acc[4][2];
#pragma unroll
    for (int i = 0; i < 4; i++) { acc[i][0] = z4; acc[i][1] = z4; }
    gemm_2x4<8, KSU, KSU>(As + lr * KSU + lq * 8,
                          u1t + (size_t)(cb + lr) * KSU + lq * 8, acc);
    __syncthreads();

#pragma unroll
    for (int ct = 0; ct < 2; ct++) {
        const int col = cb + ct * 16 + lr;
        const float bv = b1[col];
        const float bfv = bf[col];
#pragma unroll
        for (int rt = 0; rt < 4; rt++) {
#pragma unroll
            for (int r = 0; r < 4; r++) {
                const int ml = rt * 16 + lq * 4 + r;
                float v = fmaxf(acc[rt][ct][r] + bv + sF[ml] * bfv, 0.f);
                As[ml * KSU + col] = f2b(v);
            }
        }
    }
    __syncthreads();

    f32x4 acc2[4][2];
#pragma unroll
    for (int i = 0; i < 4; i++) { acc2[i][0] = z4; acc2[i][1] = z4; }
    gemm_2x4<4, KSU, KS2>(As + lr * KSU + lq * 8,
                          u2t + (size_t)(cb + lr) * KS2 + lq * 8, acc2);
    __syncthreads();

    // residual add into LN staging fp32 [64][132]
#pragma unroll
    for (int ct = 0; ct < 2; ct++) {
        const int col = cb + ct * 16 + lr;
        const float bv = b2[col];
#pragma unroll
        for (int rt = 0; rt < 4; rt++) {
#pragma unroll
            for (int r = 0; r < 4; r++) {
                const int ml = rt * 16 + lq * 4 + r;
                const int node = n0 + ml;
                if (node < N_NODES)
                    LNb[ml * 132 + col] = acc2[rt][ct][r] + bv + h_in[(size_t)node * 128 + col];
            }
        }
    }
    __syncthreads();

    {   // LayerNorm: 4 threads per row
        const int r = t >> 2, c0 = (t & 3) * 32;
        const int node = n0 + r;
        if (node < N_NODES) {
            float s = 0.f, ss = 0.f;
#pragma unroll
            for (int i = 0; i < 32; i++) { float v = LNb[r * 132 + c0 + i]; s += v; ss += v * v; }
            s += __shfl_xor(s, 1); ss += __shfl_xor(ss, 1);
            s += __shfl_xor(s, 2); ss += __shfl_xor(ss, 2);
            const float mu = s * (1.0f / 128.0f);
            const float var = ss * (1.0f / 128.0f) - mu * mu;
            const float rs = rsqrtf(var + 1e-5f);
#pragma unroll
            for (int i = 0; i < 32; i++) {
                const int j = c0 + i;
                float v = (LNb[r * 132 + j] - mu) * rs * g[j] + bet[j];
                h_out[(size_t)node * 128 + j] = v;
                hb_out[(size_t)node * 128 + j] = f2b(v);
            }
        }
    }
}

// ---------------- head GEMM ----------------
__global__ __launch_bounds__(256, 2) void head_kernel(
        const unsigned short* __restrict__ hb, const unsigned short* __restrict__ ht,
        const float* __restrict__ hbias, float* __restrict__ out) {
    __shared__ __align__(16) unsigned short As[64 * KS2];
    const int t = threadIdx.x;
    const int n0 = blockIdx.x * 64;
    {
        const int m = t >> 2, q = t & 3;
        const int node = n0 + m;
        uint4* dst = (uint4*)(As + m * KS2);
        if (node < N_NODES) {
            const uint4* s = (const uint4*)(hb + (size_t)node * 128);
#pragma unroll
            for (int i = 0; i < 4; i++) dst[q * 4 + i] = s[q * 4 + i];
        } else {
            uint4 z{0, 0, 0, 0};
            for (int i = q; i < 16; i += 4) dst[i] = z;
        }
    }
    __syncthreads();

    const int wv = t >> 6, lane = t & 63, lr = lane & 15, lq = lane >> 4;
    const int m0 = wv * 16;
    const f32x4 z4 = {0.f, 0.f, 0.f, 0.f};
    f32x4 acc[8];
#pragma unroll
    for (int i = 0; i < 8; i++) acc[i] = z4;
    gemm8<4, KS2>(As + (m0 + lr) * KS2 + lq * 8, ht + (size_t)lr * KS2 + lq * 8, acc);
#pragma unroll
    for (int ct = 0; ct < 8; ct++) {
        const int col = ct * 16 + lr;
        const float bv = hbias[col];
#pragma unroll
        for (int r = 0; r < 4; r++) {
            const int node = n0 + m0 + lq * 4 + r;
            if (node < N_NODES) out[(size_t)node * 128 + col] = acc[ct][r] + bv;
        }
    }
}

extern "C" void kernel_launch(void* const* d_in, const int* in_sizes, int n_in,
                              void* d_out, int out_size, void* d_ws, size_t ws_size,
                              hipStream_t stream) {
    const float* x       = (const float*)d_in[0];
    const int*   ei      = (const int*)d_in[1];
    const float* ea      = (const float*)d_in[2];
    const float* encW    = (const float*)d_in[3];
    const float* encb    = (const float*)d_in[4];
    const float* encg    = (const float*)d_in[5];
    const float* encbeta = (const float*)d_in[6];
    const float* msgW1   = (const float*)d_in[7];
    const float* msgb1   = (const float*)d_in[8];
    const float* msgW2   = (const float*)d_in[9];
    const float* msgb2   = (const float*)d_in[10];
    const float* updW1   = (const float*)d_in[11];
    const float* updb1   = (const float*)d_in[12];
    const float* updW2   = (const float*)d_in[13];
    const float* updb2   = (const float*)d_in[14];
    const float* lng     = (const float*)d_in[15];
    const float* lnbeta  = (const float*)d_in[16];
    const float* headW   = (const float*)d_in[17];
    const float* headb   = (const float*)d_in[18];

    char* w = (char*)d_ws;
    size_t off = 0;
    auto nxt = [&](size_t bytes) -> void* {
        void* p = w + off;
        off = (off + bytes + 255) & ~(size_t)255;
        return p;
    };
    float*          h     = (float*)nxt((size_t)N_NODES * 128 * 4);
    unsigned short* hb    = (unsigned short*)nxt((size_t)N_NODES * 128 * 2);
    float*          aggr  = (float*)nxt((size_t)N_NODES * 128 * 4);
    unsigned short* Tb    = (unsigned short*)nxt((size_t)N_NODES * 128 * 2);
    unsigned short* Sb    = (unsigned short*)nxt((size_t)N_NODES * 128 * 2);
    unsigned short* eabS  = (unsigned short*)nxt((size_t)N_EDGES * 16 * 2);
    unsigned int*   sST   = (unsigned int*)nxt((size_t)N_EDGES * 4);
    int*            hist  = (int*)nxt((size_t)N_NODES * 4);
    int*            incl  = (int*)nxt((size_t)N_NODES * 4);   // becomes cursor
    int*            blksum= (int*)nxt(256 * 4);
    unsigned short* wab   = (unsigned short*)nxt((size_t)NL * 256 * 136 * 2);
    unsigned short* w1cp  = (unsigned short*)nxt((size_t)NL * 128 * 32 * 2);
    unsigned short* u1t   = (unsigned short*)nxt((size_t)NL * 128 * KSU * 2);
    unsigned short* u2t   = (unsigned short*)nxt((size_t)NL * 128 * KS2 * 2);
    unsigned short* ht    = (unsigned short*)nxt((size_t)128 * KS2 * 2);
    float*          bfold = (float*)nxt((size_t)NL * 128 * 4);

    // permst (6.4 MB) aliases aggr (25.6 MB): permst's last use (gather_kernel)
    // strictly precedes aggr's first memset on the same stream.
    uint2*          permst = (uint2*)aggr;

    const int NBLK = (N_NODES + 255) / 256;   // 196
    const int PREP_N = NL * 256 * 136 + NL * 128 * 32 + NL * 128 * KSU
                     + NL * 128 * KS2 + 128 * KS2;

    hipMemsetAsync(hist, 0, (size_t)N_NODES * 4, stream);
    prep_kernel<<<(PREP_N + 255) / 256, 256, 0, stream>>>(msgW1, updW1, updW2, headW,
                                                          wab, w1cp, u1t, u2t, ht);
    prep2_kernel<<<NL * 128, 128, 0, stream>>>(msgW2, updW1, u1t);
    prep3_kernel<<<NL, 128, 0, stream>>>(msgb2, updW1, bfold);
    enc_kernel<<<25000, 256, 0, stream>>>(x, encW, encb, encg, encbeta, h, hb);
    hist_kernel<<<3125, 256, 0, stream>>>(ei + N_EDGES, hist);
    scan1_kernel<<<NBLK, 256, 0, stream>>>(hist, incl, blksum);
    scan2_kernel<<<1, 256, 0, stream>>>(blksum, NBLK);
    scan3_kernel<<<NBLK, 256, 0, stream>>>(incl, blksum, hist);
    scatterp_kernel<<<3125, 256, 0, stream>>>(ei, ei + N_EDGES, incl, permst);
    gather_kernel<<<3125, 256, 0, stream>>>(permst, ea, sST, eabS);

    for (int l = 0; l < NL; l++) {
        node_kernel<<<782, 256, 0, stream>>>(hb, wab + (size_t)l * 256 * 136,
                                             msgb1 + l * 128, Tb, Sb);
        hipMemsetAsync(aggr, 0, (size_t)N_NODES * 128 * 4, stream);
        edge_kernel<<<12500, 256, 0, stream>>>(eabS, sST,
                                               w1cp + (size_t)l * 128 * 32,
                                               Tb, Sb, aggr);
        upd_kernel<<<782, 256, 0, stream>>>(hb, h, aggr, hist,
                                            u1t + (size_t)l * 128 * KSU,
                                            u2t + (size_t)l * 128 * KS2,
                                            updb1 + l * 128, bfold + l * 128,
                                            updb2 + l * 128,
                                            lng + l * 128, lnbeta + l * 128, h, hb);
    }
    head_kernel<<<782, 256, 0, stream>>>(hb, ht, headb, (float*)d_out);
}

// Round 5
// 550.526 us; speedup vs baseline: 1.0454x; 1.0141x over previous
//
#include <hip/hip_runtime.h>
#include <hip/hip_bf16.h>
#include <stdint.h>

#define N_NODES 50000
#define N_EDGES 800000
#define NL 2

// K strides (bf16 elements)
#define KS2 136   // 128-K GEMMs: 4 k-steps, stride 136
#define KSU 264   // upd GEMM1: K=256 (8 k-steps), stride 264
// edge_kernel fp32 LDS stride: 132 dwords = 528B rows -> 16B-aligned (b128-capable).
// Conflicts: P1 write (16*lq+lr)%32 = 2-way (free); P3 col reads c%32 = 2-way;
// P2 b128 runs at the 8cyc/KB LDS floor.
#define ESTR 132

typedef __bf16 bf16x8 __attribute__((ext_vector_type(8)));
typedef float f32x4 __attribute__((ext_vector_type(4)));

__device__ __forceinline__ f32x4 mfma_bf16(uint4 a, uint4 b, f32x4 c) {
    return __builtin_amdgcn_mfma_f32_16x16x32_bf16(
        __builtin_bit_cast(bf16x8, a), __builtin_bit_cast(bf16x8, b), c, 0, 0, 0);
}

__device__ __forceinline__ unsigned short f2b(float f) {
    union { float f; unsigned u; } v; v.f = f;
    unsigned r = v.u + 0x7FFFu + ((v.u >> 16) & 1u);   // RNE
    return (unsigned short)(r >> 16);
}

__device__ __forceinline__ float b2f(unsigned short u) {
    union { unsigned u; float f; } v; v.u = ((unsigned)u) << 16; return v.f;
}
__device__ __forceinline__ float b2f_lo(unsigned u) {
    union { unsigned u; float f; } v; v.u = u << 16; return v.f;
}
__device__ __forceinline__ float b2f_hi(unsigned u) {
    union { unsigned u; float f; } v; v.u = u & 0xFFFF0000u; return v.f;
}

// Per-wave 16-row x 128-col tile (head_kernel).
template<int KSTEPS, int BSTR>
__device__ __forceinline__ void gemm8(const unsigned short* aLane,
                                      const unsigned short* bLane, f32x4 acc[8]) {
#pragma unroll
    for (int kc = 0; kc < KSTEPS; kc++) {
        uint4 a = *(const uint4*)(aLane + kc * 32);
#pragma unroll
        for (int ct = 0; ct < 8; ct++) {
            uint4 b = *(const uint4*)(bLane + (size_t)ct * 16 * BSTR + kc * 32);
            acc[ct] = mfma_bf16(a, b, acc[ct]);
        }
    }
}

// Column-split wave tile: 64 rows (4 rt) x 32 cols (2 ct) per wave (upd_kernel).
template<int KSTEPS, int ASTR, int BSTR>
__device__ __forceinline__ void gemm_2x4(const unsigned short* aLane,
                                         const unsigned short* bLane,
                                         f32x4 acc[4][2]) {
#pragma unroll
    for (int kc = 0; kc < KSTEPS; kc++) {
        uint4 b0 = *(const uint4*)(bLane + kc * 32);
        uint4 b1 = *(const uint4*)(bLane + (size_t)16 * BSTR + kc * 32);
#pragma unroll
        for (int rt = 0; rt < 4; rt++) {
            uint4 a = *(const uint4*)(aLane + (size_t)rt * 16 * ASTR + kc * 32);
            acc[rt][0] = mfma_bf16(a, b0, acc[rt][0]);
            acc[rt][1] = mfma_bf16(a, b1, acc[rt][1]);
        }
    }
}

// ---------------- weight prep ----------------
__global__ void prep_kernel(const float* __restrict__ mW1,
                            const float* __restrict__ uW1, const float* __restrict__ uW2,
                            const float* __restrict__ hW,
                            unsigned short* __restrict__ wab, unsigned short* __restrict__ w1cp,
                            unsigned short* __restrict__ u1t, unsigned short* __restrict__ u2t,
                            unsigned short* __restrict__ ht) {
    int i = blockIdx.x * 256 + threadIdx.x;
    const int SA = NL * 256 * 136;
    const int SC = NL * 128 * 32;
    const int SU = NL * 128 * KSU;
    const int S3 = NL * 128 * KS2;
    const int S4 = 128 * KS2;
    if (i < SA) {
        int l = i / (256 * 136), r = i % (256 * 136), j = r / 136, k = r % 136;
        float v = 0.f;
        if (k < 128)
            v = (j < 128) ? mW1[((size_t)l * 272 + k) * 128 + j]
                          : mW1[((size_t)l * 272 + 128 + k) * 128 + (j - 128)];
        wab[i] = f2b(v);
        return;
    }
    i -= SA;
    if (i < SC) {
        int l = i / (128 * 32), r = i % (128 * 32), j = r / 32, k = r % 32;
        w1cp[i] = (k < 16) ? f2b(mW1[((size_t)l * 272 + 256 + k) * 128 + j]) : (unsigned short)0;
        return;
    }
    i -= SC;
    if (i < SU) {
        int l = i / (128 * KSU), r = i % (128 * KSU), n = r / KSU, k = r % KSU;
        if (k < 128)       u1t[i] = f2b(uW1[((size_t)l * 256 + k) * 128 + n]);
        else if (k >= 256) u1t[i] = 0;
        return;
    }
    i -= SU;
    if (i < S3) {
        int l = i / (128 * KS2), r = i % (128 * KS2), n = r / KS2, k = r % KS2;
        u2t[i] = (k < 128) ? f2b(uW2[((size_t)l * 128 + k) * 128 + n]) : (unsigned short)0;
        return;
    }
    i -= S3;
    if (i < S4) {
        int n = i / KS2, k = i % KS2;
        ht[i] = (k < 128) ? f2b(hW[(size_t)k * 128 + n]) : (unsigned short)0;
    }
}

// ---------------- prep2: u1t[l][n][128+j] = bf16( sum_c W2[l][j][c] * U1[l][128+c][n] )
__global__ void prep2_kernel(const float* __restrict__ mW2, const float* __restrict__ uW1,
                             unsigned short* __restrict__ u1t) {
    __shared__ float w2row[128];
    const int l = blockIdx.x >> 7, j = blockIdx.x & 127;
    const int n = threadIdx.x;
    w2row[n] = mW2[((size_t)l * 128 + j) * 128 + n];
    __syncthreads();
    float s = 0.f;
#pragma unroll 8
    for (int c = 0; c < 128; c++)
        s += w2row[c] * uW1[((size_t)l * 256 + 128 + c) * 128 + n];
    u1t[(size_t)l * 128 * KSU + (size_t)n * KSU + 128 + j] = f2b(s);
}

// ---------------- prep3: bfold[l][n] = sum_c b2[l][c] * U1[l][128+c][n]
__global__ void prep3_kernel(const float* __restrict__ mb2, const float* __restrict__ uW1,
                             float* __restrict__ bfold) {
    const int l = blockIdx.x;
    const int n = threadIdx.x;
    float s = 0.f;
#pragma unroll 8
    for (int c = 0; c < 128; c++)
        s += mb2[l * 128 + c] * uW1[((size_t)l * 256 + 128 + c) * 128 + n];
    bfold[l * 128 + n] = s;
}

// ---------------- encoder: relu(x@W+b) -> LN ----------------
__global__ __launch_bounds__(256) void enc_kernel(
        const float* __restrict__ x, const float* __restrict__ W,
        const float* __restrict__ b, const float* __restrict__ g, const float* __restrict__ bet,
        float* __restrict__ h, unsigned short* __restrict__ hb) {
    __shared__ float sx[64];
    __shared__ float redS[4], redSS[4];
    const int t = threadIdx.x;
    const int nb = blockIdx.x * 2;           // 2 nodes / block; 25000 blocks exact
    if (t < 64) sx[t] = x[(size_t)nb * 32 + t];
    __syncthreads();
    const int half = t >> 7, j = t & 127;
    const int node = nb + half;
    float acc = b[j];
#pragma unroll
    for (int k = 0; k < 32; k++) acc += sx[half * 32 + k] * W[k * 128 + j];
    float v = fmaxf(acc, 0.f);
    float s = v, ss = v * v;
#pragma unroll
    for (int d = 32; d > 0; d >>= 1) { s += __shfl_down(s, d); ss += __shfl_down(ss, d); }
    const int wv = t >> 6;
    if ((t & 63) == 0) { redS[wv] = s; redSS[wv] = ss; }
    __syncthreads();
    float S = redS[half * 2] + redS[half * 2 + 1];
    float SS = redSS[half * 2] + redSS[half * 2 + 1];
    float mu = S * (1.f / 128.f);
    float var = SS * (1.f / 128.f) - mu * mu;
    float rs = rsqrtf(var + 1e-5f);
    float o = (v - mu) * rs * g[j] + bet[j];
    h[(size_t)node * 128 + j] = o;
    hb[(size_t)node * 128 + j] = f2b(o);
}

// ---------------- counting sort of edges by target ----------------
__global__ void hist_kernel(const int* __restrict__ tgt, int* __restrict__ hist) {
    int i = blockIdx.x * 256 + threadIdx.x;   // E = 3125*256 exact
    atomicAdd(hist + tgt[i], 1);
}

__global__ void scan1_kernel(const int* __restrict__ hist, int* __restrict__ incl,
                             int* __restrict__ blksum) {
    __shared__ int buf[256];
    const int t = threadIdx.x;
    const int i = blockIdx.x * 256 + t;
    int v = (i < N_NODES) ? hist[i] : 0;
    buf[t] = v; __syncthreads();
#pragma unroll
    for (int d = 1; d < 256; d <<= 1) {
        int x = (t >= d) ? buf[t - d] : 0;
        __syncthreads();
        buf[t] += x;
        __syncthreads();
    }
    if (i < N_NODES) incl[i] = buf[t];
    if (t == 255) blksum[blockIdx.x] = buf[255];
}

__global__ void scan2_kernel(int* __restrict__ blksum, int nblk) {
    __shared__ int buf[256];
    const int t = threadIdx.x;
    int v = (t < nblk) ? blksum[t] : 0;
    buf[t] = v; __syncthreads();
#pragma unroll
    for (int d = 1; d < 256; d <<= 1) {
        int x = (t >= d) ? buf[t - d] : 0;
        __syncthreads();
        buf[t] += x;
        __syncthreads();
    }
    if (t < nblk) blksum[t] = buf[t];
}

__global__ void scan3_kernel(int* __restrict__ incl, const int* __restrict__ blksum,
                             const int* __restrict__ hist) {
    const int i = blockIdx.x * 256 + threadIdx.x;
    if (i >= N_NODES) return;
    const int b = blockIdx.x;
    const int base = (b > 0) ? blksum[b - 1] : 0;
    incl[i] = incl[i] + base - hist[i];
}

// ---------------- sort step 1: 8B random scatter of {edge id, packed src|tgt} ------
__global__ void scatterp_kernel(const int* __restrict__ src, const int* __restrict__ tgt,
                                int* __restrict__ cursor, uint2* __restrict__ permst) {
    const int e = blockIdx.x * 256 + threadIdx.x;   // E exact
    const int tg = tgt[e];
    const int p = atomicAdd(cursor + tg, 1);
    permst[p] = make_uint2((unsigned)e, ((unsigned)src[e] << 16) | (unsigned)tg);
}

// ---------------- sort step 2: coalesced gather + bf16 convert --------------------
__global__ __launch_bounds__(256) void gather_kernel(
        const uint2* __restrict__ permst, const float* __restrict__ ea,
        unsigned int* __restrict__ sST, unsigned short* __restrict__ eabS) {
    const int p = blockIdx.x * 256 + threadIdx.x;   // E exact
    const uint2 v = permst[p];
    sST[p] = v.y;
    const float4* s = (const float4*)(ea + (size_t)v.x * 16);
    ushort4* d = (ushort4*)(eabS + (size_t)p * 16);
#pragma unroll
    for (int i = 0; i < 4; i++) {
        float4 f = s[i];
        d[i] = make_ushort4(f2b(f.x), f2b(f.y), f2b(f.z), f2b(f.w));
    }
}

// ---------------- per-layer node GEMM: T = h@W1a + b1, S = h@W1b ----------------
__global__ __launch_bounds__(256, 4) void node_kernel(
        const unsigned short* __restrict__ hb, const unsigned short* __restrict__ wab,
        const float* __restrict__ b1,
        unsigned short* __restrict__ Tb, unsigned short* __restrict__ Sb) {
    __shared__ __align__(16) unsigned short As[64 * KS2];
    const int t = threadIdx.x;
    const int n0 = blockIdx.x * 64;
    {
        const int m = t >> 2, q = t & 3;
        const int node = n0 + m;
        uint4* dst = (uint4*)(As + m * KS2);
        if (node < N_NODES) {
            const uint4* s = (const uint4*)(hb + (size_t)node * 128);
#pragma unroll
            for (int i = 0; i < 4; i++) dst[q * 4 + i] = s[q * 4 + i];
        } else {
            uint4 z{0, 0, 0, 0};
            for (int i = q; i < 16; i += 4) dst[i] = z;
        }
    }
    __syncthreads();

    const int wv = t >> 6, lane = t & 63, lr = lane & 15, lq = lane >> 4;
    const int cb = wv * 64;
    const f32x4 z4 = {0.f, 0.f, 0.f, 0.f};
    f32x4 acc[4][4];                     // [rt][ct]
#pragma unroll
    for (int i = 0; i < 4; i++)
#pragma unroll
        for (int j = 0; j < 4; j++) acc[i][j] = z4;

    const unsigned short* aL = As + lr * KS2 + lq * 8;
    const unsigned short* bL = wab + (size_t)(cb + lr) * KS2 + lq * 8;
#pragma unroll
    for (int kc = 0; kc < 4; kc++) {
        uint4 bA = *(const uint4*)(bL + kc * 32);
        uint4 bB = *(const uint4*)(bL + (size_t)16 * KS2 + kc * 32);
        uint4 bC = *(const uint4*)(bL + (size_t)32 * KS2 + kc * 32);
        uint4 bD = *(const uint4*)(bL + (size_t)48 * KS2 + kc * 32);
#pragma unroll
        for (int rt = 0; rt < 4; rt++) {
            uint4 a = *(const uint4*)(aL + (size_t)rt * 16 * KS2 + kc * 32);
            acc[rt][0] = mfma_bf16(a, bA, acc[rt][0]);
            acc[rt][1] = mfma_bf16(a, bB, acc[rt][1]);
            acc[rt][2] = mfma_bf16(a, bC, acc[rt][2]);
            acc[rt][3] = mfma_bf16(a, bD, acc[rt][3]);
        }
    }
#pragma unroll
    for (int ct = 0; ct < 4; ct++) {
        const int j = cb + ct * 16 + lr;
        const float bias = (j < 128) ? b1[j] : 0.f;
#pragma unroll
        for (int rt = 0; rt < 4; rt++) {
#pragma unroll
            for (int r = 0; r < 4; r++) {
                const int node = n0 + rt * 16 + lq * 4 + r;
                if (node < N_NODES) {
                    const float v = acc[rt][ct][r] + bias;
                    if (j < 128) Tb[(size_t)node * 128 + j] = f2b(v);
                    else         Sb[(size_t)node * 128 + (j - 128)] = f2b(v);
                }
            }
        }
    }
}

// ---------------- edge kernel: relu(T[tgt]+S[src]+ea@W1c) + segmented sum ----------------
// 64 edges/block as two 32-edge half-tiles over one fp32 LDS buffer Es[32][ESTR=132]
// (ESTR even -> 16B-aligned rows -> b128 LDS ops; the old 133 forced b32-only and
// made the LDS pipe ~95% busy = the wall).
//  - Tb/Sb gathers for half 0 are issued BEFORE P1 (hidden under MFMA+Es writes);
//    half 1's are issued during half 0's P2 (hidden under P3+P1h1). T14 pattern.
//  P1: 4 waves x (16 edges x 64 cols) MFMA ea@W1c -> Es (b32 scatter, 2-way banks).
//  P2: 256 threads consume prefetched uint4 gathers; float4 RMW of Es (b128).
//  P3: t<128, one col each; batched 8-row register loads (ds_read2-able, 8-deep ILP)
//      + SGPR ballot boundary mask; interior segments plain stores, first/last atomic.
__global__ __launch_bounds__(256, 8) void edge_kernel(
        const unsigned short* __restrict__ eabS,
        const unsigned int* __restrict__ sST,
        const unsigned short* __restrict__ w1cp,
        const unsigned short* __restrict__ Tb, const unsigned short* __restrict__ Sb,
        float* __restrict__ aggr) {
    __shared__ __align__(16) float Es[32 * ESTR];
    __shared__ int sT[64];
    __shared__ int sS[64];

    const int t = threadIdx.x;
    const int e0 = blockIdx.x * 64;          // E = 12500*64 exact
    if (t < 64) {
        const unsigned v = sST[e0 + t];
        sT[t] = (int)(v & 0xFFFFu);
        sS[t] = (int)(v >> 16);
    }
    __syncthreads();                         // A: sT/sS visible

    const int wv = t >> 6, lane = t & 63, lr = lane & 15, lq = lane >> 4;
    const int rtw = (wv >> 1) * 16;          // row-tile base within half: 0 or 16
    const int cbw = (wv & 1) * 64;           // col-block base: 0 or 64
    const int m = t & 31, c8b = t >> 5;      // P2 mapping: edge-in-half, col chunk
    const f32x4 z4 = {0.f, 0.f, 0.f, 0.f};

    // boundary ballot (wave-uniform SGPR mask, same in all waves)
    unsigned long long bmask;
    {
        const int l = t & 63;
        const int a = sT[l];
        const int b = (l > 0) ? sT[l - 1] : a;
        bmask = __ballot(a != b);
    }

    // ---- issue half-0 gathers (consumed in P2 h0; hidden under P1 h0) ----
    uint4 t0a, t0b, s0a, s0b;
    {
        const unsigned short* Tr = Tb + (size_t)sT[m] * 128;
        const unsigned short* Sr = Sb + (size_t)sS[m] * 128;
        t0a = *(const uint4*)(Tr + c8b * 8);
        t0b = *(const uint4*)(Tr + c8b * 8 + 64);
        s0a = *(const uint4*)(Sr + c8b * 8);
        s0b = *(const uint4*)(Sr + c8b * 8 + 64);
    }

    float s = 0.f;                           // P3 running segment sum (t<128)
    bool first = true;                       // first flush -> atomic; interior -> store

    {   // ---- P1 h0 ----
        uint4 a = {0, 0, 0, 0};
        if (lq < 2)
            a = *(const uint4*)(eabS + (size_t)(e0 + rtw + lr) * 16 + lq * 8);
        f32x4 acc[4];
#pragma unroll
        for (int ct = 0; ct < 4; ct++) {
            uint4 b = *(const uint4*)(w1cp + (cbw + ct * 16 + lr) * 32 + lq * 8);
            acc[ct] = mfma_bf16(a, b, z4);
        }
#pragma unroll
        for (int ct = 0; ct < 4; ct++) {
            const int col = cbw + ct * 16 + lr;
#pragma unroll
            for (int r = 0; r < 4; r++)
                Es[(rtw + lq * 4 + r) * ESTR + col] = acc[ct][r];
        }
    }
    __syncthreads();                         // B

    uint4 t1a, t1b, s1a, s1b;
    {   // ---- P2 h0: consume prefetch, float4 RMW ----
        float* Erow = Es + m * ESTR;
        float4* EA = (float4*)(Erow + c8b * 8);
        float4* EB = (float4*)(Erow + c8b * 8 + 64);
        float4 ea0 = EA[0], ea1 = EA[1];
        ea0.x = fmaxf(ea0.x + b2f_lo(t0a.x) + b2f_lo(s0a.x), 0.f);
        ea0.y = fmaxf(ea0.y + b2f_hi(t0a.x) + b2f_hi(s0a.x), 0.f);
        ea0.z = fmaxf(ea0.z + b2f_lo(t0a.y) + b2f_lo(s0a.y), 0.f);
        ea0.w = fmaxf(ea0.w + b2f_hi(t0a.y) + b2f_hi(s0a.y), 0.f);
        ea1.x = fmaxf(ea1.x + b2f_lo(t0a.z) + b2f_lo(s0a.z), 0.f);
        ea1.y = fmaxf(ea1.y + b2f_hi(t0a.z) + b2f_hi(s0a.z), 0.f);
        ea1.z = fmaxf(ea1.z + b2f_lo(t0a.w) + b2f_lo(s0a.w), 0.f);
        ea1.w = fmaxf(ea1.w + b2f_hi(t0a.w) + b2f_hi(s0a.w), 0.f);
        EA[0] = ea0; EA[1] = ea1;
        float4 eb0 = EB[0], eb1 = EB[1];
        eb0.x = fmaxf(eb0.x + b2f_lo(t0b.x) + b2f_lo(s0b.x), 0.f);
        eb0.y = fmaxf(eb0.y + b2f_hi(t0b.x) + b2f_hi(s0b.x), 0.f);
        eb0.z = fmaxf(eb0.z + b2f_lo(t0b.y) + b2f_lo(s0b.y), 0.f);
        eb0.w = fmaxf(eb0.w + b2f_hi(t0b.y) + b2f_hi(s0b.y), 0.f);
        eb1.x = fmaxf(eb1.x + b2f_lo(t0b.z) + b2f_lo(s0b.z), 0.f);
        eb1.y = fmaxf(eb1.y + b2f_hi(t0b.z) + b2f_hi(s0b.z), 0.f);
        eb1.z = fmaxf(eb1.z + b2f_lo(t0b.w) + b2f_lo(s0b.w), 0.f);
        eb1.w = fmaxf(eb1.w + b2f_hi(t0b.w) + b2f_hi(s0b.w), 0.f);
        EB[0] = eb0; EB[1] = eb1;

        // ---- issue half-1 gathers (consumed in P2 h1; hidden under P3 h0 + P1 h1)
        const unsigned short* Tr = Tb + (size_t)sT[32 + m] * 128;
        const unsigned short* Sr = Sb + (size_t)sS[32 + m] * 128;
        t1a = *(const uint4*)(Tr + c8b * 8);
        t1b = *(const uint4*)(Tr + c8b * 8 + 64);
        s1a = *(const uint4*)(Sr + c8b * 8);
        s1b = *(const uint4*)(Sr + c8b * 8 + 64);
    }
    __syncthreads();                         // C

    if (t < 128) {   // ---- P3 h0: col c = t, rows 0..31, batched loads ----
        const int c = t;
        const unsigned mh = (unsigned)bmask;
#pragma unroll
        for (int i8 = 0; i8 < 4; i8++) {
            float v[8];
#pragma unroll
            for (int j = 0; j < 8; j++) v[j] = Es[(i8 * 8 + j) * ESTR + c];
#pragma unroll
            for (int j = 0; j < 8; j++) {
                const int i = i8 * 8 + j;
                if (mh & (1u << i)) {        // wave-uniform scalar branch
                    float* dst = aggr + (size_t)sT[i - 1] * 128 + c;
                    if (first) { atomicAdd(dst, s); first = false; }
                    else       { *dst = s; }
                    s = 0.f;
                }
                s += v[j];
            }
        }
    }
    __syncthreads();                         // D: Es free for h1

    {   // ---- P1 h1 ----
        uint4 a = {0, 0, 0, 0};
        if (lq < 2)
            a = *(const uint4*)(eabS + (size_t)(e0 + 32 + rtw + lr) * 16 + lq * 8);
        f32x4 acc[4];
#pragma unroll
        for (int ct = 0; ct < 4; ct++) {
            uint4 b = *(const uint4*)(w1cp + (cbw + ct * 16 + lr) * 32 + lq * 8);
            acc[ct] = mfma_bf16(a, b, z4);
        }
#pragma unroll
        for (int ct = 0; ct < 4; ct++) {
            const int col = cbw + ct * 16 + lr;
#pragma unroll
            for (int r = 0; r < 4; r++)
                Es[(rtw + lq * 4 + r) * ESTR + col] = acc[ct][r];
        }
    }
    __syncthreads();                         // E

    {   // ---- P2 h1 ----
        float* Erow = Es + m * ESTR;
        float4* EA = (float4*)(Erow + c8b * 8);
        float4* EB = (float4*)(Erow + c8b * 8 + 64);
        float4 ea0 = EA[0], ea1 = EA[1];
        ea0.x = fmaxf(ea0.x + b2f_lo(t1a.x) + b2f_lo(s1a.x), 0.f);
        ea0.y = fmaxf(ea0.y + b2f_hi(t1a.x) + b2f_hi(s1a.x), 0.f);
        ea0.z = fmaxf(ea0.z + b2f_lo(t1a.y) + b2f_lo(s1a.y), 0.f);
        ea0.w = fmaxf(ea0.w + b2f_hi(t1a.y) + b2f_hi(s1a.y), 0.f);
        ea1.x = fmaxf(ea1.x + b2f_lo(t1a.z) + b2f_lo(s1a.z), 0.f);
        ea1.y = fmaxf(ea1.y + b2f_hi(t1a.z) + b2f_hi(s1a.z), 0.f);
        ea1.z = fmaxf(ea1.z + b2f_lo(t1a.w) + b2f_lo(s1a.w), 0.f);
        ea1.w = fmaxf(ea1.w + b2f_hi(t1a.w) + b2f_hi(s1a.w), 0.f);
        EA[0] = ea0; EA[1] = ea1;
        float4 eb0 = EB[0], eb1 = EB[1];
        eb0.x = fmaxf(eb0.x + b2f_lo(t1b.x) + b2f_lo(s1b.x), 0.f);
        eb0.y = fmaxf(eb0.y + b2f_hi(t1b.x) + b2f_hi(s1b.x), 0.f);
        eb0.z = fmaxf(eb0.z + b2f_lo(t1b.y) + b2f_lo(s1b.y), 0.f);
        eb0.w = fmaxf(eb0.w + b2f_hi(t1b.y) + b2f_hi(s1b.y), 0.f);
        eb1.x = fmaxf(eb1.x + b2f_lo(t1b.z) + b2f_lo(s1b.z), 0.f);
        eb1.y = fmaxf(eb1.y + b2f_hi(t1b.z) + b2f_hi(s1b.z), 0.f);
        eb1.z = fmaxf(eb1.z + b2f_lo(t1b.w) + b2f_lo(s1b.w), 0.f);
        eb1.w = fmaxf(eb1.w + b2f_hi(t1b.w) + b2f_hi(s1b.w), 0.f);
        EB[0] = eb0; EB[1] = eb1;
    }
    __syncthreads();                         // F

    if (t < 128) {   // ---- P3 h1: rows 32..63 ----
        const int c = t;
        const unsigned mh = (unsigned)(bmask >> 32);
#pragma unroll
        for (int i8 = 0; i8 < 4; i8++) {
            float v[8];
#pragma unroll
            for (int j = 0; j < 8; j++) v[j] = Es[(i8 * 8 + j) * ESTR + c];
#pragma unroll
            for (int j = 0; j < 8; j++) {
                const int i = i8 * 8 + j;
                if (mh & (1u << i)) {
                    float* dst = aggr + (size_t)sT[32 + i - 1] * 128 + c;
                    if (first) { atomicAdd(dst, s); first = false; }
                    else       { *dst = s; }
                    s = 0.f;
                }
                s += v[j];
            }
        }
        atomicAdd(aggr + (size_t)sT[63] * 128 + c, s);   // may span blocks
    }
}

// ---------------- update MLP + residual + LN ----------------
__global__ __launch_bounds__(256, 4) void upd_kernel(
        const unsigned short* __restrict__ hb_in, const float* __restrict__ h_in,
        const float* __restrict__ aggr, const int* __restrict__ hist,
        const unsigned short* __restrict__ u1t, const unsigned short* __restrict__ u2t,
        const float* __restrict__ b1, const float* __restrict__ bf,
        const float* __restrict__ b2,
        const float* __restrict__ g, const float* __restrict__ bet,
        float* __restrict__ h_out, unsigned short* __restrict__ hb_out) {
    __shared__ __align__(16) char smemA[64 * KSU * 2];
    __shared__ float sF[64];
    unsigned short* As = (unsigned short*)smemA;
    float* LNb = (float*)smemA;

    const int t = threadIdx.x;
    const int n0 = blockIdx.x * 64;
    {
        const int m = t >> 2, q = t & 3;
        const int node = n0 + m;
        unsigned short* row = As + m * KSU;
        if (node < N_NODES) {
            const uint4* ph = (const uint4*)(hb_in + (size_t)node * 128);
            uint4* d0 = (uint4*)row;
#pragma unroll
            for (int i = 0; i < 4; i++) d0[q * 4 + i] = ph[q * 4 + i];
            const int cntv = hist[node];
            if (q == 0) sF[m] = (cntv > 0) ? 1.f : 0.f;
            const float rden = 1.0f / fmaxf((float)cntv, 1.0f);
            const float4* pa = (const float4*)(aggr + (size_t)node * 128 + q * 32);
            ushort4* d1 = (ushort4*)(row + 128 + q * 32);
#pragma unroll
            for (int i = 0; i < 8; i++) {
                float4 v = pa[i];
                d1[i] = make_ushort4(f2b(v.x * rden), f2b(v.y * rden),
                                     f2b(v.z * rden), f2b(v.w * rden));
            }
            if (q == 0) { uint4 z{0, 0, 0, 0}; ((uint4*)(row + 256))[0] = z; }
        } else {
            if (q == 0) sF[m] = 0.f;
            uint4 z{0, 0, 0, 0};
            uint4* d = (uint4*)row;
            for (int i = q; i < 33; i += 4) d[i] = z;
        }
    }
    __syncthreads();

    const int wv = t >> 6, lane = t & 63, lr = lane & 15, lq = lane >> 4;
    const int cb = wv * 32;
    const f32x4 z4 = {0.f, 0.f, 0.f, 0.f};

    f32x4 acc[4][2];
#pragma unroll
    for (int i = 0; i < 4; i++) { acc[i][0] = z4; acc[i][1] = z4; }
    gemm_2x4<8, KSU, KSU>(As + lr * KSU + lq * 8,
                          u1t + (size_t)(cb + lr) * KSU + lq * 8, acc);
    __syncthreads();

#pragma unroll
    for (int ct = 0; ct < 2; ct++) {
        const int col = cb + ct * 16 + lr;
        const float bv = b1[col];
        const float bfv = bf[col];
#pragma unroll
        for (int rt = 0; rt < 4; rt++) {
#pragma unroll
            for (int r = 0; r < 4; r++) {
                const int ml = rt * 16 + lq * 4 + r;
                float v = fmaxf(acc[rt][ct][r] + bv + sF[ml] * bfv, 0.f);
                As[ml * KSU + col] = f2b(v);
            }
        }
    }
    __syncthreads();

    f32x4 acc2[4][2];
#pragma unroll
    for (int i = 0; i < 4; i++) { acc2[i][0] = z4; acc2[i][1] = z4; }
    gemm_2x4<4, KSU, KS2>(As + lr * KSU + lq * 8,
                          u2t + (size_t)(cb + lr) * KS2 + lq * 8, acc2);
    __syncthreads();

    // residual add into LN staging fp32 [64][132]
#pragma unroll
    for (int ct = 0; ct < 2; ct++) {
        const int col = cb + ct * 16 + lr;
        const float bv = b2[col];
#pragma unroll
        for (int rt = 0; rt < 4; rt++) {
#pragma unroll
            for (int r = 0; r < 4; r++) {
                const int ml = rt * 16 + lq * 4 + r;
                const int node = n0 + ml;
                if (node < N_NODES)
                    LNb[ml * 132 + col] = acc2[rt][ct][r] + bv + h_in[(size_t)node * 128 + col];
            }
        }
    }
    __syncthreads();

    {   // LayerNorm: 4 threads per row
        const int r = t >> 2, c0 = (t & 3) * 32;
        const int node = n0 + r;
        if (node < N_NODES) {
            float s = 0.f, ss = 0.f;
#pragma unroll
            for (int i = 0; i < 32; i++) { float v = LNb[r * 132 + c0 + i]; s += v; ss += v * v; }
            s += __shfl_xor(s, 1); ss += __shfl_xor(ss, 1);
            s += __shfl_xor(s, 2); ss += __shfl_xor(ss, 2);
            const float mu = s * (1.0f / 128.0f);
            const float var = ss * (1.0f / 128.0f) - mu * mu;
            const float rs = rsqrtf(var + 1e-5f);
#pragma unroll
            for (int i = 0; i < 32; i++) {
                const int j = c0 + i;
                float v = (LNb[r * 132 + j] - mu) * rs * g[j] + bet[j];
                h_out[(size_t)node * 128 + j] = v;
                hb_out[(size_t)node * 128 + j] = f2b(v);
            }
        }
    }
}

// ---------------- head GEMM ----------------
__global__ __launch_bounds__(256, 2) void head_kernel(
        const unsigned short* __restrict__ hb, const unsigned short* __restrict__ ht,
        const float* __restrict__ hbias, float* __restrict__ out) {
    __shared__ __align__(16) unsigned short As[64 * KS2];
    const int t = threadIdx.x;
    const int n0 = blockIdx.x * 64;
    {
        const int m = t >> 2, q = t & 3;
        const int node = n0 + m;
        uint4* dst = (uint4*)(As + m * KS2);
        if (node < N_NODES) {
            const uint4* s = (const uint4*)(hb + (size_t)node * 128);
#pragma unroll
            for (int i = 0; i < 4; i++) dst[q * 4 + i] = s[q * 4 + i];
        } else {
            uint4 z{0, 0, 0, 0};
            for (int i = q; i < 16; i += 4) dst[i] = z;
        }
    }
    __syncthreads();

    const int wv = t >> 6, lane = t & 63, lr = lane & 15, lq = lane >> 4;
    const int m0 = wv * 16;
    const f32x4 z4 = {0.f, 0.f, 0.f, 0.f};
    f32x4 acc[8];
#pragma unroll
    for (int i = 0; i < 8; i++) acc[i] = z4;
    gemm8<4, KS2>(As + (m0 + lr) * KS2 + lq * 8, ht + (size_t)lr * KS2 + lq * 8, acc);
#pragma unroll
    for (int ct = 0; ct < 8; ct++) {
        const int col = ct * 16 + lr;
        const float bv = hbias[col];
#pragma unroll
        for (int r = 0; r < 4; r++) {
            const int node = n0 + m0 + lq * 4 + r;
            if (node < N_NODES) out[(size_t)node * 128 + col] = acc[ct][r] + bv;
        }
    }
}

extern "C" void kernel_launch(void* const* d_in, const int* in_sizes, int n_in,
                              void* d_out, int out_size, void* d_ws, size_t ws_size,
                              hipStream_t stream) {
    const float* x       = (const float*)d_in[0];
    const int*   ei      = (const int*)d_in[1];
    const float* ea      = (const float*)d_in[2];
    const float* encW    = (const float*)d_in[3];
    const float* encb    = (const float*)d_in[4];
    const float* encg    = (const float*)d_in[5];
    const float* encbeta = (const float*)d_in[6];
    const float* msgW1   = (const float*)d_in[7];
    const float* msgb1   = (const float*)d_in[8];
    const float* msgW2   = (const float*)d_in[9];
    const float* msgb2   = (const float*)d_in[10];
    const float* updW1   = (const float*)d_in[11];
    const float* updb1   = (const float*)d_in[12];
    const float* updW2   = (const float*)d_in[13];
    const float* updb2   = (const float*)d_in[14];
    const float* lng     = (const float*)d_in[15];
    const float* lnbeta  = (const float*)d_in[16];
    const float* headW   = (const float*)d_in[17];
    const float* headb   = (const float*)d_in[18];

    char* w = (char*)d_ws;
    size_t off = 0;
    auto nxt = [&](size_t bytes) -> void* {
        void* p = w + off;
        off = (off + bytes + 255) & ~(size_t)255;
        return p;
    };
    float*          h     = (float*)nxt((size_t)N_NODES * 128 * 4);
    unsigned short* hb    = (unsigned short*)nxt((size_t)N_NODES * 128 * 2);
    float*          aggr  = (float*)nxt((size_t)N_NODES * 128 * 4);
    unsigned short* Tb    = (unsigned short*)nxt((size_t)N_NODES * 128 * 2);
    unsigned short* Sb    = (unsigned short*)nxt((size_t)N_NODES * 128 * 2);
    unsigned short* eabS  = (unsigned short*)nxt((size_t)N_EDGES * 16 * 2);
    unsigned int*   sST   = (unsigned int*)nxt((size_t)N_EDGES * 4);
    int*            hist  = (int*)nxt((size_t)N_NODES * 4);
    int*            incl  = (int*)nxt((size_t)N_NODES * 4);   // becomes cursor
    int*            blksum= (int*)nxt(256 * 4);
    unsigned short* wab   = (unsigned short*)nxt((size_t)NL * 256 * 136 * 2);
    unsigned short* w1cp  = (unsigned short*)nxt((size_t)NL * 128 * 32 * 2);
    unsigned short* u1t   = (unsigned short*)nxt((size_t)NL * 128 * KSU * 2);
    unsigned short* u2t   = (unsigned short*)nxt((size_t)NL * 128 * KS2 * 2);
    unsigned short* ht    = (unsigned short*)nxt((size_t)128 * KS2 * 2);
    float*          bfold = (float*)nxt((size_t)NL * 128 * 4);

    // permst (6.4 MB) aliases aggr (25.6 MB): permst's last use (gather_kernel)
    // strictly precedes aggr's first memset on the same stream.
    uint2*          permst = (uint2*)aggr;

    const int NBLK = (N_NODES + 255) / 256;   // 196
    const int PREP_N = NL * 256 * 136 + NL * 128 * 32 + NL * 128 * KSU
                     + NL * 128 * KS2 + 128 * KS2;

    hipMemsetAsync(hist, 0, (size_t)N_NODES * 4, stream);
    prep_kernel<<<(PREP_N + 255) / 256, 256, 0, stream>>>(msgW1, updW1, updW2, headW,
                                                          wab, w1cp, u1t, u2t, ht);
    prep2_kernel<<<NL * 128, 128, 0, stream>>>(msgW2, updW1, u1t);
    prep3_kernel<<<NL, 128, 0, stream>>>(msgb2, updW1, bfold);
    enc_kernel<<<25000, 256, 0, stream>>>(x, encW, encb, encg, encbeta, h, hb);
    hist_kernel<<<3125, 256, 0, stream>>>(ei + N_EDGES, hist);
    scan1_kernel<<<NBLK, 256, 0, stream>>>(hist, incl, blksum);
    scan2_kernel<<<1, 256, 0, stream>>>(blksum, NBLK);
    scan3_kernel<<<NBLK, 256, 0, stream>>>(incl, blksum, hist);
    scatterp_kernel<<<3125, 256, 0, stream>>>(ei, ei + N_EDGES, incl, permst);
    gather_kernel<<<3125, 256, 0, stream>>>(permst, ea, sST, eabS);

    for (int l = 0; l < NL; l++) {
        node_kernel<<<782, 256, 0, stream>>>(hb, wab + (size_t)l * 256 * 136,
                                             msgb1 + l * 128, Tb, Sb);
        hipMemsetAsync(aggr, 0, (size_t)N_NODES * 128 * 4, stream);
        edge_kernel<<<12500, 256, 0, stream>>>(eabS, sST,
                                               w1cp + (size_t)l * 128 * 32,
                                               Tb, Sb, aggr);
        upd_kernel<<<782, 256, 0, stream>>>(hb, h, aggr, hist,
                                            u1t + (size_t)l * 128 * KSU,
                                            u2t + (size_t)l * 128 * KS2,
                                            updb1 + l * 128, bfold + l * 128,
                                            updb2 + l * 128,
                                            lng + l * 128, lnbeta + l * 128, h, hb);
    }
    head_kernel<<<782, 256, 0, stream>>>(hb, ht, headb, (float*)d_out);
}